// Round 6
// baseline (169.612 us; speedup 1.0000x reference)
//
#include <hip/hip_runtime.h>
#include <hip/hip_bf16.h>

#define NN 1500
#define GIN 32
#define GOUT 8
#define HID 128
#define CAP 192           // max nnz/row kept; mean ~60, sigma ~7.6 -> 17 sigma headroom

// ---------------------------------------------------------------------------
// Fused: compact combined adjacency row (geo+sem > 0) into LDS, write CSR for
// layers 2-3, and compute GAT layer 1 attention for this row in one kernel.
// One block (256 thr) per row.
// ---------------------------------------------------------------------------
__global__ void gat_first(const float* __restrict__ geo,
                          const float* __restrict__ sem,
                          const float* __restrict__ feat,   // NN x 32
                          const float* __restrict__ W0,     // 32 x 8
                          const float* __restrict__ a0,     // 16
                          int* __restrict__ csr_idx,
                          float* __restrict__ csr_val,
                          int* __restrict__ csr_cnt,
                          float* __restrict__ enc_out) {
    const int i = blockIdx.x;
    const int t = threadIdx.x;  // 256
    __shared__ int cnt;
    __shared__ int sidx[CAP];
    __shared__ float sval[CAP];
    __shared__ float hi_s[GOUT];
    __shared__ float wsum[4][GOUT + 1];
    if (t == 0) cnt = 0;
    __syncthreads();

    const float* grow = geo + (size_t)i * NN;
    const float* srow = sem + (size_t)i * NN;
    for (int q = t; q < NN / 4; q += 256) {
        float4 g = *(const float4*)(grow + 4 * q);
        float4 s = *(const float4*)(srow + 4 * q);
        float a[4] = {g.x + s.x, g.y + s.y, g.z + s.z, g.w + s.w};
        #pragma unroll
        for (int c = 0; c < 4; ++c) {
            if (a[c] > 0.f) {
                int p = atomicAdd(&cnt, 1);
                if (p < CAP) { sidx[p] = 4 * q + c; sval[p] = a[c]; }
            }
        }
    }
    // h_i (only needed for f_src): threads 0..7
    if (t < GOUT) {
        float hv = 0.f;
        #pragma unroll 4
        for (int c = 0; c < GIN; ++c)
            hv = fmaf(feat[(size_t)i * GIN + c], W0[c * GOUT + t], hv);
        hi_s[t] = hv;
    }
    __syncthreads();

    const int c2 = cnt < CAP ? cnt : CAP;
    if (t == 0) csr_cnt[i] = c2;
    for (int p = t; p < c2; p += 256) {
        csr_idx[(size_t)i * CAP + p] = sidx[p];
        csr_val[(size_t)i * CAP + p] = sval[p];
    }
    float fsrc = 0.f;
    #pragma unroll
    for (int k = 0; k < GOUT; ++k) fsrc = fmaf(hi_s[k], a0[k], fsrc);

    // attention: one entry per thread (cnt <= 192 < 256 -> single pass)
    float den = 0.f;
    float num[GOUT] = {};
    if (t < c2) {
        int j = sidx[t];
        float a = sval[t];
        float hj[GOUT] = {};
        #pragma unroll
        for (int c4 = 0; c4 < GIN / 4; ++c4) {
            float4 e4 = *(const float4*)(feat + (size_t)j * GIN + 4 * c4);
            const float* ep = (const float*)&e4;
            #pragma unroll
            for (int c = 0; c < 4; ++c)
                #pragma unroll
                for (int k = 0; k < GOUT; ++k)
                    hj[k] = fmaf(ep[c], W0[(4 * c4 + c) * GOUT + k], hj[k]);
        }
        float fd = 0.f;
        #pragma unroll
        for (int k = 0; k < GOUT; ++k) fd = fmaf(hj[k], a0[GOUT + k], fd);
        float ev = fsrc + fd;
        ev = (ev > 0.f) ? ev : 0.2f * ev;
        ev *= a;
        float p = __expf(ev);
        den = p;
        #pragma unroll
        for (int k = 0; k < GOUT; ++k) num[k] = p * hj[k];
    }
    #pragma unroll
    for (int off = 32; off > 0; off >>= 1) {
        den += __shfl_xor(den, off, 64);
        #pragma unroll
        for (int k = 0; k < GOUT; ++k) num[k] += __shfl_xor(num[k], off, 64);
    }
    if ((t & 63) == 0) {
        wsum[t >> 6][0] = den;
        #pragma unroll
        for (int k = 0; k < GOUT; ++k) wsum[t >> 6][1 + k] = num[k];
    }
    __syncthreads();
    if (t < GOUT) {
        float L = wsum[0][0] + wsum[1][0] + wsum[2][0] + wsum[3][0];
        float v = (wsum[0][1 + t] + wsum[1][1 + t] + wsum[2][1 + t] + wsum[3][1 + t]) / L;
        enc_out[(size_t)i * GOUT + t] = (v > 0.f) ? v : (__expf(v) - 1.f);
    }
}

// ---------------------------------------------------------------------------
// GAT layers 2,3: one WAVE per row i, CSR-driven. When UV=true (layer 3),
// the wave also computes U[i,:], V[i,:], A[i]=sum_k U*f2, B[i]=sum_k V*f2
// (rank-1 split of the MLP, see mlp_kernel), and row 0's wave writes
// c = sum_k w16[k]*f2[k].
// ---------------------------------------------------------------------------
template<int IN, bool UV>
__global__ void gat_layer(const float* __restrict__ enc,
                          const float* __restrict__ W,     // IN x 8
                          const float* __restrict__ avec,  // 16
                          const int* __restrict__ csr_idx,
                          const float* __restrict__ csr_val,
                          const int* __restrict__ csr_cnt,
                          float* __restrict__ enc_out,
                          const float* __restrict__ fc1w,  // 17 x 128
                          const float* __restrict__ fc1b,  // 128
                          const float* __restrict__ fc2w,  // 128
                          float* __restrict__ Ubuf, float* __restrict__ Vbuf,
                          float* __restrict__ Arow, float* __restrict__ Bcol,
                          float* __restrict__ cptr) {
    const int tid = threadIdx.x;            // 256 = 4 waves, 1 wave per row
    const int lane = tid & 63;
    const int i = blockIdx.x * 4 + (tid >> 6);   // 375*4 == 1500 exact

    float hv = 0.f;
    if (lane < GOUT) {
        #pragma unroll 4
        for (int c = 0; c < IN; ++c)
            hv = fmaf(enc[(size_t)i * IN + c], W[c * GOUT + lane], hv);
    }
    float hi[GOUT];
    #pragma unroll
    for (int c = 0; c < GOUT; ++c) hi[c] = __shfl(hv, c, 64);
    float fsrc = 0.f;
    #pragma unroll
    for (int c = 0; c < GOUT; ++c) fsrc = fmaf(hi[c], avec[c], fsrc);

    const int cnt = csr_cnt[i];
    float den = 0.f;
    float num[GOUT] = {};
    for (int e = lane; e < cnt; e += 64) {
        int j = csr_idx[(size_t)i * CAP + e];
        float a = csr_val[(size_t)i * CAP + e];
        float hj[GOUT] = {};
        #pragma unroll
        for (int c4 = 0; c4 < IN / 4; ++c4) {
            float4 e4 = *(const float4*)(enc + (size_t)j * IN + 4 * c4);
            const float* ep = (const float*)&e4;
            #pragma unroll
            for (int c = 0; c < 4; ++c)
                #pragma unroll
                for (int k = 0; k < GOUT; ++k)
                    hj[k] = fmaf(ep[c], W[(4 * c4 + c) * GOUT + k], hj[k]);
        }
        float fd = 0.f;
        #pragma unroll
        for (int k = 0; k < GOUT; ++k) fd = fmaf(hj[k], avec[GOUT + k], fd);
        float ev = fsrc + fd;
        ev = (ev > 0.f) ? ev : 0.2f * ev;
        ev *= a;
        float p = __expf(ev);
        den += p;
        #pragma unroll
        for (int k = 0; k < GOUT; ++k) num[k] = fmaf(p, hj[k], num[k]);
    }
    #pragma unroll
    for (int off = 32; off > 0; off >>= 1) {
        den += __shfl_xor(den, off, 64);
        #pragma unroll
        for (int k = 0; k < GOUT; ++k) num[k] += __shfl_xor(num[k], off, 64);
    }
    // elu output for this row (valid at lanes 0..7)
    float vout = 0.f;
    if (lane < GOUT) {
        float v = num[lane] / den;
        vout = (v > 0.f) ? v : (__expf(v) - 1.f);
        enc_out[(size_t)i * GOUT + lane] = vout;
    }

    if constexpr (UV) {
        float er[GOUT];
        #pragma unroll
        for (int c = 0; c < GOUT; ++c) er[c] = __shfl(vout, c, 64);
        const int kl = lane, kh = lane + 64;
        float u_lo = fc1b[kl], u_hi = fc1b[kh];
        float v_lo = 0.f, v_hi = 0.f;
        #pragma unroll
        for (int c = 0; c < GOUT; ++c) {
            u_lo = fmaf(er[c], fc1w[c * HID + kl], u_lo);
            u_hi = fmaf(er[c], fc1w[c * HID + kh], u_hi);
            v_lo = fmaf(er[c], fc1w[(GOUT + c) * HID + kl], v_lo);
            v_hi = fmaf(er[c], fc1w[(GOUT + c) * HID + kh], v_hi);
        }
        Ubuf[(size_t)i * HID + kl] = u_lo;
        Ubuf[(size_t)i * HID + kh] = u_hi;
        Vbuf[(size_t)i * HID + kl] = v_lo;
        Vbuf[(size_t)i * HID + kh] = v_hi;
        const float f_lo = fc2w[kl], f_hi = fc2w[kh];
        float ap = u_lo * f_lo + u_hi * f_hi;
        float bp = v_lo * f_lo + v_hi * f_hi;
        #pragma unroll
        for (int off = 32; off > 0; off >>= 1) {
            ap += __shfl_xor(ap, off, 64);
            bp += __shfl_xor(bp, off, 64);
        }
        if (lane == 0) { Arow[i] = ap; Bcol[i] = bp; }
        if (i == 0) {
            const float* w16g = fc1w + 2 * GOUT * HID;
            float cp = w16g[kl] * f_lo + w16g[kh] * f_hi;
            #pragma unroll
            for (int off = 32; off > 0; off >>= 1) cp += __shfl_xor(cp, off, 64);
            if (lane == 0) cptr[0] = cp;
        }
    }
}

// ---------------------------------------------------------------------------
// Pair-MLP with the relu->abs rank-1 split:
//   t_k = U[i,k] + V[j,k] + d*w16[k]
//   out[i,j] = fc2b + 0.5*(A_i + B_j + d*c) + 0.5*sum_k |t_k|*f2[k]
// (relu(x) = (x+|x|)/2 exactly; linear half is rank-1, precomputed in layer 3)
// Inner loop: 3 VALU per k per output (add, fma, fma-with-|src|-modifier).
// 64x64 tile, 4x4/thread, grid 24x24=576; LDS 34.8 KB -> up to 4 blocks/CU.
// ---------------------------------------------------------------------------
#define BT 64
#define KS 64
#define KSTR 68   // 64+4 pad: U rows -> 4 distinct banks + broadcast, V -> 2-way (free)

__global__ __launch_bounds__(256, 4) void mlp_kernel(
        const float* __restrict__ U, const float* __restrict__ V,
        const float* __restrict__ Arow, const float* __restrict__ Bcol,
        const float* __restrict__ cptr,
        const float* __restrict__ dist,
        const float* __restrict__ fc1w,   // 17 x 128 (row 16 = w16)
        const float* __restrict__ fc2w,   // 128
        const float* __restrict__ fc2b,   // 1
        float* __restrict__ out) {
    __shared__ float Us[BT * KSTR];
    __shared__ float Vs[BT * KSTR];

    const int tid = threadIdx.x;
    const int i0 = blockIdx.y * BT;
    const int j0 = blockIdx.x * BT;
    const int tx = tid & 15;
    const int ty = tid >> 4;

    const float* w16g = fc1w + 2 * GOUT * HID;

    // distance tile: 16 scalars, persist in registers across both k-phases
    int irow[4], jcol[4];
    float d[4][4];
    #pragma unroll
    for (int ii = 0; ii < 4; ++ii) irow[ii] = i0 + ty + 16 * ii;
    #pragma unroll
    for (int jj = 0; jj < 4; ++jj) jcol[jj] = j0 + tx + 16 * jj;
    #pragma unroll
    for (int ii = 0; ii < 4; ++ii) {
        int ic = irow[ii] < NN ? irow[ii] : NN - 1;
        #pragma unroll
        for (int jj = 0; jj < 4; ++jj) {
            int jc = jcol[jj] < NN ? jcol[jj] : NN - 1;
            d[ii][jj] = dist[(size_t)ic * NN + jc];
        }
    }

    float acc[4][4] = {};

    #pragma unroll
    for (int ph = 0; ph < 2; ++ph) {
        const int k0 = ph * KS;
        if (ph) __syncthreads();
        // stage U (64x16 f4) then V (64x16 f4): 2048 units, 8/thread, pure copy
        for (int u = tid; u < 2 * BT * 16; u += 256) {
            const int isU = (u < BT * 16);
            const int q = isU ? u : u - BT * 16;
            const int r = q >> 4;
            const int kq = (q & 15) << 2;
            int g = (isU ? i0 : j0) + r;
            if (g >= NN) g = NN - 1;
            float4 val = *(const float4*)((isU ? U : V) + (size_t)g * HID + k0 + kq);
            *(float4*)((isU ? Us : Vs) + r * KSTR + kq) = val;
        }
        __syncthreads();

        #pragma unroll 2
        for (int k4 = 0; k4 < KS; k4 += 4) {
            float4 u4[4], v4[4];
            #pragma unroll
            for (int ii = 0; ii < 4; ++ii)
                u4[ii] = *(const float4*)(Us + (ty + 16 * ii) * KSTR + k4);
            #pragma unroll
            for (int jj = 0; jj < 4; ++jj)
                v4[jj] = *(const float4*)(Vs + (tx + 16 * jj) * KSTR + k4);
            // wave-uniform k -> scalar s_load, no VALU/LDS cost
            float wv[4], fv[4];
            #pragma unroll
            for (int kk = 0; kk < 4; ++kk) {
                wv[kk] = w16g[k0 + k4 + kk];
                fv[kk] = fc2w[k0 + k4 + kk];
            }
            #pragma unroll
            for (int kk = 0; kk < 4; ++kk) {
                #pragma unroll
                for (int ii = 0; ii < 4; ++ii) {
                    float uk = ((const float*)&u4[ii])[kk];
                    #pragma unroll
                    for (int jj = 0; jj < 4; ++jj) {
                        float t = fmaf(d[ii][jj], wv[kk],
                                       uk + ((const float*)&v4[jj])[kk]);
                        acc[ii][jj] = fmaf(fabsf(t), fv[kk], acc[ii][jj]);
                    }
                }
            }
        }
    }

    // epilogue: combine with rank-1 linear half
    const float c = cptr[0];
    const float b2 = fc2b[0];
    #pragma unroll
    for (int ii = 0; ii < 4; ++ii) {
        if (irow[ii] >= NN) continue;
        const float Ai = Arow[irow[ii]];
        #pragma unroll
        for (int jj = 0; jj < 4; ++jj) {
            if (jcol[jj] >= NN) continue;
            float lin = Ai + Bcol[jcol[jj]] + d[ii][jj] * c;
            out[(size_t)irow[ii] * NN + jcol[jj]] = fmaf(0.5f, lin + acc[ii][jj], b2);
        }
    }
}

// ---------------------------------------------------------------------------
extern "C" void kernel_launch(void* const* d_in, const int* in_sizes, int n_in,
                              void* d_out, int out_size, void* d_ws, size_t ws_size,
                              hipStream_t stream) {
    const float* geo  = (const float*)d_in[0];
    const float* sem  = (const float*)d_in[1];
    const float* feat = (const float*)d_in[2];
    // d_in[3] = region_pairs: full meshgrid -> row-major (i,j); unused
    const float* dist = (const float*)d_in[4];
    const float* W0   = (const float*)d_in[5];
    const float* W1   = (const float*)d_in[6];
    const float* W2   = (const float*)d_in[7];
    const float* a0   = (const float*)d_in[8];
    const float* a1   = (const float*)d_in[9];
    const float* a2   = (const float*)d_in[10];
    const float* fc1w = (const float*)d_in[11];
    const float* fc1b = (const float*)d_in[12];
    const float* fc2w = (const float*)d_in[13];
    const float* fc2b = (const float*)d_in[14];
    float* out = (float*)d_out;

    // workspace layout (~4.2 MB); all chunk sizes keep 16B alignment
    char* ws = (char*)d_ws;
    int*   csr_idx = (int*)ws;                         ws += sizeof(int) * NN * CAP;
    float* csr_val = (float*)ws;                       ws += sizeof(float) * NN * CAP;
    int*   csr_cnt = (int*)ws;                         ws += sizeof(int) * NN;
    float* encA    = (float*)ws;                       ws += sizeof(float) * NN * GOUT;
    float* encB    = (float*)ws;                       ws += sizeof(float) * NN * GOUT;
    float* Ubuf    = (float*)ws;                       ws += sizeof(float) * NN * HID;
    float* Vbuf    = (float*)ws;                       ws += sizeof(float) * NN * HID;
    float* Ar      = (float*)ws;                       ws += sizeof(float) * NN;
    float* Bc      = (float*)ws;                       ws += sizeof(float) * NN;
    float* cptr    = (float*)ws;

    gat_first<<<NN, 256, 0, stream>>>(geo, sem, feat, W0, a0,
                                      csr_idx, csr_val, csr_cnt, encA);
    gat_layer<GOUT, false><<<NN / 4, 256, 0, stream>>>(
        encA, W1, a1, csr_idx, csr_val, csr_cnt, encB,
        nullptr, nullptr, nullptr, nullptr, nullptr, nullptr, nullptr, nullptr);
    gat_layer<GOUT, true><<<NN / 4, 256, 0, stream>>>(
        encB, W2, a2, csr_idx, csr_val, csr_cnt, encA,
        fc1w, fc1b, fc2w, Ubuf, Vbuf, Ar, Bc, cptr);

    dim3 mg((NN + BT - 1) / BT, (NN + BT - 1) / BT);  // 24 x 24
    mlp_kernel<<<mg, 256, 0, stream>>>(Ubuf, Vbuf, Ar, Bc, cptr,
                                       dist, fc1w, fc2w, fc2b, out);
}

// Round 7
// 167.454 us; speedup vs baseline: 1.0129x; 1.0129x over previous
//
#include <hip/hip_runtime.h>
#include <hip/hip_bf16.h>

#define NN 1500
#define GIN 32
#define GOUT 8
#define HID 128
#define CAP 192           // max nnz/row kept; mean ~60, sigma ~7.6 -> 17 sigma headroom

// ---------------------------------------------------------------------------
// Fused: compact combined adjacency row (geo+sem > 0) into LDS, write CSR for
// layers 2-3, and compute GAT layer 1 attention for this row in one kernel.
// One block (256 thr) per row.
// ---------------------------------------------------------------------------
__global__ void gat_first(const float* __restrict__ geo,
                          const float* __restrict__ sem,
                          const float* __restrict__ feat,   // NN x 32
                          const float* __restrict__ W0,     // 32 x 8
                          const float* __restrict__ a0,     // 16
                          int* __restrict__ csr_idx,
                          float* __restrict__ csr_val,
                          int* __restrict__ csr_cnt,
                          float* __restrict__ enc_out) {
    const int i = blockIdx.x;
    const int t = threadIdx.x;  // 256
    __shared__ int cnt;
    __shared__ int sidx[CAP];
    __shared__ float sval[CAP];
    __shared__ float hi_s[GOUT];
    __shared__ float wsum[4][GOUT + 1];
    if (t == 0) cnt = 0;
    __syncthreads();

    const float* grow = geo + (size_t)i * NN;
    const float* srow = sem + (size_t)i * NN;
    for (int q = t; q < NN / 4; q += 256) {
        float4 g = *(const float4*)(grow + 4 * q);
        float4 s = *(const float4*)(srow + 4 * q);
        float a[4] = {g.x + s.x, g.y + s.y, g.z + s.z, g.w + s.w};
        #pragma unroll
        for (int c = 0; c < 4; ++c) {
            if (a[c] > 0.f) {
                int p = atomicAdd(&cnt, 1);
                if (p < CAP) { sidx[p] = 4 * q + c; sval[p] = a[c]; }
            }
        }
    }
    // h_i (only needed for f_src): threads 0..7
    if (t < GOUT) {
        float hv = 0.f;
        #pragma unroll 4
        for (int c = 0; c < GIN; ++c)
            hv = fmaf(feat[(size_t)i * GIN + c], W0[c * GOUT + t], hv);
        hi_s[t] = hv;
    }
    __syncthreads();

    const int c2 = cnt < CAP ? cnt : CAP;
    if (t == 0) csr_cnt[i] = c2;
    for (int p = t; p < c2; p += 256) {
        csr_idx[(size_t)i * CAP + p] = sidx[p];
        csr_val[(size_t)i * CAP + p] = sval[p];
    }
    float fsrc = 0.f;
    #pragma unroll
    for (int k = 0; k < GOUT; ++k) fsrc = fmaf(hi_s[k], a0[k], fsrc);

    // attention: one entry per thread (cnt <= 192 < 256 -> single pass)
    float den = 0.f;
    float num[GOUT] = {};
    if (t < c2) {
        int j = sidx[t];
        float a = sval[t];
        float hj[GOUT] = {};
        #pragma unroll
        for (int c4 = 0; c4 < GIN / 4; ++c4) {
            float4 e4 = *(const float4*)(feat + (size_t)j * GIN + 4 * c4);
            const float* ep = (const float*)&e4;
            #pragma unroll
            for (int c = 0; c < 4; ++c)
                #pragma unroll
                for (int k = 0; k < GOUT; ++k)
                    hj[k] = fmaf(ep[c], W0[(4 * c4 + c) * GOUT + k], hj[k]);
        }
        float fd = 0.f;
        #pragma unroll
        for (int k = 0; k < GOUT; ++k) fd = fmaf(hj[k], a0[GOUT + k], fd);
        float ev = fsrc + fd;
        ev = (ev > 0.f) ? ev : 0.2f * ev;
        ev *= a;
        float p = __expf(ev);
        den = p;
        #pragma unroll
        for (int k = 0; k < GOUT; ++k) num[k] = p * hj[k];
    }
    #pragma unroll
    for (int off = 32; off > 0; off >>= 1) {
        den += __shfl_xor(den, off, 64);
        #pragma unroll
        for (int k = 0; k < GOUT; ++k) num[k] += __shfl_xor(num[k], off, 64);
    }
    if ((t & 63) == 0) {
        wsum[t >> 6][0] = den;
        #pragma unroll
        for (int k = 0; k < GOUT; ++k) wsum[t >> 6][1 + k] = num[k];
    }
    __syncthreads();
    if (t < GOUT) {
        float L = wsum[0][0] + wsum[1][0] + wsum[2][0] + wsum[3][0];
        float v = (wsum[0][1 + t] + wsum[1][1 + t] + wsum[2][1 + t] + wsum[3][1 + t]) / L;
        enc_out[(size_t)i * GOUT + t] = (v > 0.f) ? v : (__expf(v) - 1.f);
    }
}

// ---------------------------------------------------------------------------
// GAT layers 2,3: one WAVE per row i, CSR-driven. When UV=true (layer 3),
// the wave also computes U[i,:], V[i,:], A[i]=sum_k U*f2, B[i]=sum_k V*f2
// (rank-1 split of the MLP), and row 0's wave writes c = sum_k w16[k]*f2[k].
// ---------------------------------------------------------------------------
template<int IN, bool UV>
__global__ void gat_layer(const float* __restrict__ enc,
                          const float* __restrict__ W,     // IN x 8
                          const float* __restrict__ avec,  // 16
                          const int* __restrict__ csr_idx,
                          const float* __restrict__ csr_val,
                          const int* __restrict__ csr_cnt,
                          float* __restrict__ enc_out,
                          const float* __restrict__ fc1w,  // 17 x 128
                          const float* __restrict__ fc1b,  // 128
                          const float* __restrict__ fc2w,  // 128
                          float* __restrict__ Ubuf, float* __restrict__ Vbuf,
                          float* __restrict__ Arow, float* __restrict__ Bcol,
                          float* __restrict__ cptr) {
    const int tid = threadIdx.x;            // 256 = 4 waves, 1 wave per row
    const int lane = tid & 63;
    const int i = blockIdx.x * 4 + (tid >> 6);   // 375*4 == 1500 exact

    float hv = 0.f;
    if (lane < GOUT) {
        #pragma unroll 4
        for (int c = 0; c < IN; ++c)
            hv = fmaf(enc[(size_t)i * IN + c], W[c * GOUT + lane], hv);
    }
    float hi[GOUT];
    #pragma unroll
    for (int c = 0; c < GOUT; ++c) hi[c] = __shfl(hv, c, 64);
    float fsrc = 0.f;
    #pragma unroll
    for (int c = 0; c < GOUT; ++c) fsrc = fmaf(hi[c], avec[c], fsrc);

    const int cnt = csr_cnt[i];
    float den = 0.f;
    float num[GOUT] = {};
    for (int e = lane; e < cnt; e += 64) {
        int j = csr_idx[(size_t)i * CAP + e];
        float a = csr_val[(size_t)i * CAP + e];
        float hj[GOUT] = {};
        #pragma unroll
        for (int c4 = 0; c4 < IN / 4; ++c4) {
            float4 e4 = *(const float4*)(enc + (size_t)j * IN + 4 * c4);
            const float* ep = (const float*)&e4;
            #pragma unroll
            for (int c = 0; c < 4; ++c)
                #pragma unroll
                for (int k = 0; k < GOUT; ++k)
                    hj[k] = fmaf(ep[c], W[(4 * c4 + c) * GOUT + k], hj[k]);
        }
        float fd = 0.f;
        #pragma unroll
        for (int k = 0; k < GOUT; ++k) fd = fmaf(hj[k], avec[GOUT + k], fd);
        float ev = fsrc + fd;
        ev = (ev > 0.f) ? ev : 0.2f * ev;
        ev *= a;
        float p = __expf(ev);
        den += p;
        #pragma unroll
        for (int k = 0; k < GOUT; ++k) num[k] = fmaf(p, hj[k], num[k]);
    }
    #pragma unroll
    for (int off = 32; off > 0; off >>= 1) {
        den += __shfl_xor(den, off, 64);
        #pragma unroll
        for (int k = 0; k < GOUT; ++k) num[k] += __shfl_xor(num[k], off, 64);
    }
    // elu output for this row (valid at lanes 0..7)
    float vout = 0.f;
    if (lane < GOUT) {
        float v = num[lane] / den;
        vout = (v > 0.f) ? v : (__expf(v) - 1.f);
        enc_out[(size_t)i * GOUT + lane] = vout;
    }

    if constexpr (UV) {
        float er[GOUT];
        #pragma unroll
        for (int c = 0; c < GOUT; ++c) er[c] = __shfl(vout, c, 64);
        const int kl = lane, kh = lane + 64;
        float u_lo = fc1b[kl], u_hi = fc1b[kh];
        float v_lo = 0.f, v_hi = 0.f;
        #pragma unroll
        for (int c = 0; c < GOUT; ++c) {
            u_lo = fmaf(er[c], fc1w[c * HID + kl], u_lo);
            u_hi = fmaf(er[c], fc1w[c * HID + kh], u_hi);
            v_lo = fmaf(er[c], fc1w[(GOUT + c) * HID + kl], v_lo);
            v_hi = fmaf(er[c], fc1w[(GOUT + c) * HID + kh], v_hi);
        }
        Ubuf[(size_t)i * HID + kl] = u_lo;
        Ubuf[(size_t)i * HID + kh] = u_hi;
        Vbuf[(size_t)i * HID + kl] = v_lo;
        Vbuf[(size_t)i * HID + kh] = v_hi;
        const float f_lo = fc2w[kl], f_hi = fc2w[kh];
        float ap = u_lo * f_lo + u_hi * f_hi;
        float bp = v_lo * f_lo + v_hi * f_hi;
        #pragma unroll
        for (int off = 32; off > 0; off >>= 1) {
            ap += __shfl_xor(ap, off, 64);
            bp += __shfl_xor(bp, off, 64);
        }
        if (lane == 0) { Arow[i] = ap; Bcol[i] = bp; }
        if (i == 0) {
            const float* w16g = fc1w + 2 * GOUT * HID;
            float cp = w16g[kl] * f_lo + w16g[kh] * f_hi;
            #pragma unroll
            for (int off = 32; off > 0; off >>= 1) cp += __shfl_xor(cp, off, 64);
            if (lane == 0) cptr[0] = cp;
        }
    }
}

// ---------------------------------------------------------------------------
// Pair-MLP, relu->abs rank-1 split, K SPLIT BY 2 ACROSS blockIdx.z:
//   t_k = U[i,k] + V[j,k] + d*w16[k]
//   out[i,j] = fc2b + 0.5*(A_i + B_j + d*c) + 0.5*sum_k |t_k|*f2[k]
// Each z-block computes sum over its 64 k's and atomicAdd's 0.5*partial into
// the pre-zeroed out; z=0 also adds the rank-1 half + bias. Exactly 2
// commutative fp32 adds per element -> deterministic.
// Grid 24x24x2 = 1152 blocks = 4.5/CU; LDS 34.8 KB -> 4 resident blocks =
// 16 waves/CU (2x round 6) to cover ds_read latency (R6: VALUBusy 43%).
// ---------------------------------------------------------------------------
#define BT 64
#define KS 64
#define KSTR 68   // 64+4 pad: rows ty -> banks 4*ty (distinct), 2-way j -> free

__global__ __launch_bounds__(256, 4) void mlp_kernel(
        const float* __restrict__ U, const float* __restrict__ V,
        const float* __restrict__ Arow, const float* __restrict__ Bcol,
        const float* __restrict__ cptr,
        const float* __restrict__ dist,
        const float* __restrict__ fc1w,   // 17 x 128 (row 16 = w16)
        const float* __restrict__ fc2w,   // 128
        const float* __restrict__ fc2b,   // 1
        float* __restrict__ out) {
    __shared__ float Us[BT * KSTR];
    __shared__ float Vs[BT * KSTR];

    const int tid = threadIdx.x;
    const int i0 = blockIdx.y * BT;
    const int j0 = blockIdx.x * BT;
    const int k0 = blockIdx.z * KS;
    const int tx = tid & 15;
    const int ty = tid >> 4;

    const float* w16g = fc1w + 2 * GOUT * HID;

    // stage U (64x16 f4) then V (64x16 f4): 2048 units, 8/thread, pure copy
    for (int u = tid; u < 2 * BT * 16; u += 256) {
        const int isU = (u < BT * 16);
        const int q = isU ? u : u - BT * 16;
        const int r = q >> 4;
        const int kq = (q & 15) << 2;
        int g = (isU ? i0 : j0) + r;
        if (g >= NN) g = NN - 1;
        float4 val = *(const float4*)((isU ? U : V) + (size_t)g * HID + k0 + kq);
        *(float4*)((isU ? Us : Vs) + r * KSTR + kq) = val;
    }

    // distance tile: 16 scalars in registers
    int irow[4], jcol[4];
    float d[4][4];
    #pragma unroll
    for (int ii = 0; ii < 4; ++ii) irow[ii] = i0 + ty + 16 * ii;
    #pragma unroll
    for (int jj = 0; jj < 4; ++jj) jcol[jj] = j0 + tx + 16 * jj;
    #pragma unroll
    for (int ii = 0; ii < 4; ++ii) {
        int ic = irow[ii] < NN ? irow[ii] : NN - 1;
        #pragma unroll
        for (int jj = 0; jj < 4; ++jj) {
            int jc = jcol[jj] < NN ? jcol[jj] : NN - 1;
            d[ii][jj] = dist[(size_t)ic * NN + jc];
        }
    }
    __syncthreads();

    float acc[4][4] = {};
    #pragma unroll 2
    for (int k4 = 0; k4 < KS; k4 += 4) {
        float4 u4[4], v4[4];
        #pragma unroll
        for (int ii = 0; ii < 4; ++ii)
            u4[ii] = *(const float4*)(Us + (ty + 16 * ii) * KSTR + k4);
        #pragma unroll
        for (int jj = 0; jj < 4; ++jj)
            v4[jj] = *(const float4*)(Vs + (tx + 16 * jj) * KSTR + k4);
        // wave-uniform k -> scalar s_load, no VALU/LDS cost
        float wv[4], fv[4];
        #pragma unroll
        for (int kk = 0; kk < 4; ++kk) {
            wv[kk] = w16g[k0 + k4 + kk];
            fv[kk] = fc2w[k0 + k4 + kk];
        }
        #pragma unroll
        for (int kk = 0; kk < 4; ++kk) {
            #pragma unroll
            for (int ii = 0; ii < 4; ++ii) {
                float uk = ((const float*)&u4[ii])[kk];
                #pragma unroll
                for (int jj = 0; jj < 4; ++jj) {
                    float t = fmaf(d[ii][jj], wv[kk],
                                   uk + ((const float*)&v4[jj])[kk]);
                    acc[ii][jj] = fmaf(__builtin_fabsf(t), fv[kk], acc[ii][jj]);
                }
            }
        }
    }

    // epilogue: atomic accumulate (out pre-zeroed; 2 commutative adds/elem)
    if (k0 == 0) {
        const float c = cptr[0];
        const float b2 = fc2b[0];
        #pragma unroll
        for (int ii = 0; ii < 4; ++ii) {
            if (irow[ii] >= NN) continue;
            const float Ai = Arow[irow[ii]];
            #pragma unroll
            for (int jj = 0; jj < 4; ++jj) {
                if (jcol[jj] >= NN) continue;
                float lin = Ai + Bcol[jcol[jj]] + d[ii][jj] * c;
                atomicAdd(&out[(size_t)irow[ii] * NN + jcol[jj]],
                          fmaf(0.5f, lin + acc[ii][jj], b2));
            }
        }
    } else {
        #pragma unroll
        for (int ii = 0; ii < 4; ++ii) {
            if (irow[ii] >= NN) continue;
            #pragma unroll
            for (int jj = 0; jj < 4; ++jj) {
                if (jcol[jj] >= NN) continue;
                atomicAdd(&out[(size_t)irow[ii] * NN + jcol[jj]],
                          0.5f * acc[ii][jj]);
            }
        }
    }
}

// ---------------------------------------------------------------------------
extern "C" void kernel_launch(void* const* d_in, const int* in_sizes, int n_in,
                              void* d_out, int out_size, void* d_ws, size_t ws_size,
                              hipStream_t stream) {
    const float* geo  = (const float*)d_in[0];
    const float* sem  = (const float*)d_in[1];
    const float* feat = (const float*)d_in[2];
    // d_in[3] = region_pairs: full meshgrid -> row-major (i,j); unused
    const float* dist = (const float*)d_in[4];
    const float* W0   = (const float*)d_in[5];
    const float* W1   = (const float*)d_in[6];
    const float* W2   = (const float*)d_in[7];
    const float* a0   = (const float*)d_in[8];
    const float* a1   = (const float*)d_in[9];
    const float* a2   = (const float*)d_in[10];
    const float* fc1w = (const float*)d_in[11];
    const float* fc1b = (const float*)d_in[12];
    const float* fc2w = (const float*)d_in[13];
    const float* fc2b = (const float*)d_in[14];
    float* out = (float*)d_out;

    // workspace layout (~4.2 MB); all chunk sizes keep 16B alignment
    char* ws = (char*)d_ws;
    int*   csr_idx = (int*)ws;                         ws += sizeof(int) * NN * CAP;
    float* csr_val = (float*)ws;                       ws += sizeof(float) * NN * CAP;
    int*   csr_cnt = (int*)ws;                         ws += sizeof(int) * NN;
    float* encA    = (float*)ws;                       ws += sizeof(float) * NN * GOUT;
    float* encB    = (float*)ws;                       ws += sizeof(float) * NN * GOUT;
    float* Ubuf    = (float*)ws;                       ws += sizeof(float) * NN * HID;
    float* Vbuf    = (float*)ws;                       ws += sizeof(float) * NN * HID;
    float* Ar      = (float*)ws;                       ws += sizeof(float) * NN;
    float* Bc      = (float*)ws;                       ws += sizeof(float) * NN;
    float* cptr    = (float*)ws;

    // zero the output for the atomic k-split accumulation (async, capturable)
    hipMemsetAsync(out, 0, sizeof(float) * (size_t)NN * NN, stream);

    gat_first<<<NN, 256, 0, stream>>>(geo, sem, feat, W0, a0,
                                      csr_idx, csr_val, csr_cnt, encA);
    gat_layer<GOUT, false><<<NN / 4, 256, 0, stream>>>(
        encA, W1, a1, csr_idx, csr_val, csr_cnt, encB,
        nullptr, nullptr, nullptr, nullptr, nullptr, nullptr, nullptr, nullptr);
    gat_layer<GOUT, true><<<NN / 4, 256, 0, stream>>>(
        encB, W2, a2, csr_idx, csr_val, csr_cnt, encA,
        fc1w, fc1b, fc2w, Ubuf, Vbuf, Ar, Bc, cptr);

    dim3 mg((NN + BT - 1) / BT, (NN + BT - 1) / BT, 2);  // 24 x 24 x 2
    mlp_kernel<<<mg, 256, 0, stream>>>(Ubuf, Vbuf, Ar, Bc, cptr,
                                       dist, fc1w, fc2w, fc2b, out);
}

// Round 8
// 156.851 us; speedup vs baseline: 1.0814x; 1.0676x over previous
//
#include <hip/hip_runtime.h>
#include <hip/hip_bf16.h>

#define NN 1500
#define GIN 32
#define GOUT 8
#define HID 128
#define CAP 192           // max nnz/row kept; mean ~60, sigma ~7.6 -> 17 sigma headroom

// ---------------------------------------------------------------------------
// Fused: compact combined adjacency row (geo+sem > 0) into LDS, write CSR for
// layers 2-3, and compute GAT layer 1 attention for this row in one kernel.
// One block (256 thr) per row.
// ---------------------------------------------------------------------------
__global__ void gat_first(const float* __restrict__ geo,
                          const float* __restrict__ sem,
                          const float* __restrict__ feat,   // NN x 32
                          const float* __restrict__ W0,     // 32 x 8
                          const float* __restrict__ a0,     // 16
                          int* __restrict__ csr_idx,
                          float* __restrict__ csr_val,
                          int* __restrict__ csr_cnt,
                          float* __restrict__ enc_out) {
    const int i = blockIdx.x;
    const int t = threadIdx.x;  // 256
    __shared__ int cnt;
    __shared__ int sidx[CAP];
    __shared__ float sval[CAP];
    __shared__ float hi_s[GOUT];
    __shared__ float wsum[4][GOUT + 1];
    if (t == 0) cnt = 0;
    __syncthreads();

    const float* grow = geo + (size_t)i * NN;
    const float* srow = sem + (size_t)i * NN;
    for (int q = t; q < NN / 4; q += 256) {
        float4 g = *(const float4*)(grow + 4 * q);
        float4 s = *(const float4*)(srow + 4 * q);
        float a[4] = {g.x + s.x, g.y + s.y, g.z + s.z, g.w + s.w};
        #pragma unroll
        for (int c = 0; c < 4; ++c) {
            if (a[c] > 0.f) {
                int p = atomicAdd(&cnt, 1);
                if (p < CAP) { sidx[p] = 4 * q + c; sval[p] = a[c]; }
            }
        }
    }
    // h_i (only needed for f_src): threads 0..7
    if (t < GOUT) {
        float hv = 0.f;
        #pragma unroll 4
        for (int c = 0; c < GIN; ++c)
            hv = fmaf(feat[(size_t)i * GIN + c], W0[c * GOUT + t], hv);
        hi_s[t] = hv;
    }
    __syncthreads();

    const int c2 = cnt < CAP ? cnt : CAP;
    if (t == 0) csr_cnt[i] = c2;
    for (int p = t; p < c2; p += 256) {
        csr_idx[(size_t)i * CAP + p] = sidx[p];
        csr_val[(size_t)i * CAP + p] = sval[p];
    }
    float fsrc = 0.f;
    #pragma unroll
    for (int k = 0; k < GOUT; ++k) fsrc = fmaf(hi_s[k], a0[k], fsrc);

    // attention: one entry per thread (cnt <= 192 < 256 -> single pass)
    float den = 0.f;
    float num[GOUT] = {};
    if (t < c2) {
        int j = sidx[t];
        float a = sval[t];
        float hj[GOUT] = {};
        #pragma unroll
        for (int c4 = 0; c4 < GIN / 4; ++c4) {
            float4 e4 = *(const float4*)(feat + (size_t)j * GIN + 4 * c4);
            const float* ep = (const float*)&e4;
            #pragma unroll
            for (int c = 0; c < 4; ++c)
                #pragma unroll
                for (int k = 0; k < GOUT; ++k)
                    hj[k] = fmaf(ep[c], W0[(4 * c4 + c) * GOUT + k], hj[k]);
        }
        float fd = 0.f;
        #pragma unroll
        for (int k = 0; k < GOUT; ++k) fd = fmaf(hj[k], a0[GOUT + k], fd);
        float ev = fsrc + fd;
        ev = (ev > 0.f) ? ev : 0.2f * ev;
        ev *= a;
        float p = __expf(ev);
        den = p;
        #pragma unroll
        for (int k = 0; k < GOUT; ++k) num[k] = p * hj[k];
    }
    #pragma unroll
    for (int off = 32; off > 0; off >>= 1) {
        den += __shfl_xor(den, off, 64);
        #pragma unroll
        for (int k = 0; k < GOUT; ++k) num[k] += __shfl_xor(num[k], off, 64);
    }
    if ((t & 63) == 0) {
        wsum[t >> 6][0] = den;
        #pragma unroll
        for (int k = 0; k < GOUT; ++k) wsum[t >> 6][1 + k] = num[k];
    }
    __syncthreads();
    if (t < GOUT) {
        float L = wsum[0][0] + wsum[1][0] + wsum[2][0] + wsum[3][0];
        float v = (wsum[0][1 + t] + wsum[1][1 + t] + wsum[2][1 + t] + wsum[3][1 + t]) / L;
        enc_out[(size_t)i * GOUT + t] = (v > 0.f) ? v : (__expf(v) - 1.f);
    }
}

// ---------------------------------------------------------------------------
// GAT layers 2,3: one WAVE per row i, CSR-driven. When UV=true (layer 3),
// the wave also computes U[i,:], V[i,:], A[i]=sum_k U*f2, B[i]=sum_k V*f2
// (rank-1 split of the MLP), and row 0's wave writes c = sum_k w16[k]*f2[k].
// ---------------------------------------------------------------------------
template<int IN, bool UV>
__global__ void gat_layer(const float* __restrict__ enc,
                          const float* __restrict__ W,     // IN x 8
                          const float* __restrict__ avec,  // 16
                          const int* __restrict__ csr_idx,
                          const float* __restrict__ csr_val,
                          const int* __restrict__ csr_cnt,
                          float* __restrict__ enc_out,
                          const float* __restrict__ fc1w,  // 17 x 128
                          const float* __restrict__ fc1b,  // 128
                          const float* __restrict__ fc2w,  // 128
                          float* __restrict__ Ubuf, float* __restrict__ Vbuf,
                          float* __restrict__ Arow, float* __restrict__ Bcol,
                          float* __restrict__ cptr) {
    const int tid = threadIdx.x;            // 256 = 4 waves, 1 wave per row
    const int lane = tid & 63;
    const int i = blockIdx.x * 4 + (tid >> 6);   // 375*4 == 1500 exact

    float hv = 0.f;
    if (lane < GOUT) {
        #pragma unroll 4
        for (int c = 0; c < IN; ++c)
            hv = fmaf(enc[(size_t)i * IN + c], W[c * GOUT + lane], hv);
    }
    float hi[GOUT];
    #pragma unroll
    for (int c = 0; c < GOUT; ++c) hi[c] = __shfl(hv, c, 64);
    float fsrc = 0.f;
    #pragma unroll
    for (int c = 0; c < GOUT; ++c) fsrc = fmaf(hi[c], avec[c], fsrc);

    const int cnt = csr_cnt[i];
    float den = 0.f;
    float num[GOUT] = {};
    for (int e = lane; e < cnt; e += 64) {
        int j = csr_idx[(size_t)i * CAP + e];
        float a = csr_val[(size_t)i * CAP + e];
        float hj[GOUT] = {};
        #pragma unroll
        for (int c4 = 0; c4 < IN / 4; ++c4) {
            float4 e4 = *(const float4*)(enc + (size_t)j * IN + 4 * c4);
            const float* ep = (const float*)&e4;
            #pragma unroll
            for (int c = 0; c < 4; ++c)
                #pragma unroll
                for (int k = 0; k < GOUT; ++k)
                    hj[k] = fmaf(ep[c], W[(4 * c4 + c) * GOUT + k], hj[k]);
        }
        float fd = 0.f;
        #pragma unroll
        for (int k = 0; k < GOUT; ++k) fd = fmaf(hj[k], avec[GOUT + k], fd);
        float ev = fsrc + fd;
        ev = (ev > 0.f) ? ev : 0.2f * ev;
        ev *= a;
        float p = __expf(ev);
        den += p;
        #pragma unroll
        for (int k = 0; k < GOUT; ++k) num[k] = fmaf(p, hj[k], num[k]);
    }
    #pragma unroll
    for (int off = 32; off > 0; off >>= 1) {
        den += __shfl_xor(den, off, 64);
        #pragma unroll
        for (int k = 0; k < GOUT; ++k) num[k] += __shfl_xor(num[k], off, 64);
    }
    // elu output for this row (valid at lanes 0..7)
    float vout = 0.f;
    if (lane < GOUT) {
        float v = num[lane] / den;
        vout = (v > 0.f) ? v : (__expf(v) - 1.f);
        enc_out[(size_t)i * GOUT + lane] = vout;
    }

    if constexpr (UV) {
        float er[GOUT];
        #pragma unroll
        for (int c = 0; c < GOUT; ++c) er[c] = __shfl(vout, c, 64);
        const int kl = lane, kh = lane + 64;
        float u_lo = fc1b[kl], u_hi = fc1b[kh];
        float v_lo = 0.f, v_hi = 0.f;
        #pragma unroll
        for (int c = 0; c < GOUT; ++c) {
            u_lo = fmaf(er[c], fc1w[c * HID + kl], u_lo);
            u_hi = fmaf(er[c], fc1w[c * HID + kh], u_hi);
            v_lo = fmaf(er[c], fc1w[(GOUT + c) * HID + kl], v_lo);
            v_hi = fmaf(er[c], fc1w[(GOUT + c) * HID + kh], v_hi);
        }
        Ubuf[(size_t)i * HID + kl] = u_lo;
        Ubuf[(size_t)i * HID + kh] = u_hi;
        Vbuf[(size_t)i * HID + kl] = v_lo;
        Vbuf[(size_t)i * HID + kh] = v_hi;
        const float f_lo = fc2w[kl], f_hi = fc2w[kh];
        float ap = u_lo * f_lo + u_hi * f_hi;
        float bp = v_lo * f_lo + v_hi * f_hi;
        #pragma unroll
        for (int off = 32; off > 0; off >>= 1) {
            ap += __shfl_xor(ap, off, 64);
            bp += __shfl_xor(bp, off, 64);
        }
        if (lane == 0) { Arow[i] = ap; Bcol[i] = bp; }
        if (i == 0) {
            const float* w16g = fc1w + 2 * GOUT * HID;
            float cp = w16g[kl] * f_lo + w16g[kh] * f_hi;
            #pragma unroll
            for (int off = 32; off > 0; off >>= 1) cp += __shfl_xor(cp, off, 64);
            if (lane == 0) cptr[0] = cp;
        }
    }
}

// ---------------------------------------------------------------------------
// Pair-MLP, LDS-FREE (R4-R7 invariant: LDS-staged tiles pinned VALUBusy ~47%).
// lane = column j (wave = 64 consecutive j), i-block of 12 rows per block-row:
//   V[j,k]           -> per-lane VGPRs, reused across the 12 i rows
//   U[i,k],w16,f2    -> wave-uniform -> s_load (SMEM pipe), <=1 SGPR per VALU op
//   d[i,j]           -> per-lane VGPR (coalesced column loads, once)
//   out = fc2b + 0.5*(A_i + B_j + d*c) + 0.5*sum_k |U+V+d*w16|*f2   (relu->abs)
// 3 VALU/k/output (v_add, v_fma, v_fma with free |abs| modifier), no ds_read,
// no barriers, no atomics, plain coalesced stores. Grid 6 x 125 = 750 blocks,
// 3000 waves ~ 2.9/SIMD.
// ---------------------------------------------------------------------------
#define IB 12
#define KC 16

__global__ __launch_bounds__(256, 4) void mlp_kernel(
        const float* __restrict__ U, const float* __restrict__ V,
        const float* __restrict__ Arow, const float* __restrict__ Bcol,
        const float* __restrict__ cptr,
        const float* __restrict__ dist,
        const float* __restrict__ fc1w,   // 17 x 128 (row 16 = w16)
        const float* __restrict__ fc2w,   // 128
        const float* __restrict__ fc2b,   // 1
        float* __restrict__ out) {
    const int tid = threadIdx.x;
    const int j = blockIdx.x * 256 + tid;        // 6*256 = 1536 covers 1500
    const int jc = j < NN ? j : NN - 1;
    const int i0 = blockIdx.y * IB;              // 125*12 = 1500 exact
    const float* w16g = fc1w + 2 * GOUT * HID;

    // distance column strip + accumulators (per-lane registers)
    float d[IB], acc[IB];
    #pragma unroll
    for (int r = 0; r < IB; ++r) {
        d[r] = dist[(size_t)(i0 + r) * NN + jc];
        acc[r] = 0.f;
    }

    const float* Vrow = V + (size_t)jc * HID;
    for (int kc = 0; kc < HID; kc += KC) {   // 8 chunks
        // per-lane V chunk
        float v[KC];
        #pragma unroll
        for (int q = 0; q < KC; q += 4)
            *(float4*)(v + q) = *(const float4*)(Vrow + kc + q);
        // wave-uniform chunks -> SGPRs
        float wv[KC], fv[KC];
        #pragma unroll
        for (int q = 0; q < KC; q += 4) {
            *(float4*)(wv + q) = *(const float4*)(w16g + kc + q);
            *(float4*)(fv + q) = *(const float4*)(fc2w + kc + q);
        }
        #pragma unroll
        for (int r = 0; r < IB; ++r) {
            const float* Urow = U + (size_t)(i0 + r) * HID + kc;  // uniform
            #pragma unroll
            for (int q = 0; q < KC; q += 4) {
                float4 u4 = *(const float4*)(Urow + q);           // s_load x4
                const float* up = (const float*)&u4;
                #pragma unroll
                for (int k = 0; k < 4; ++k) {
                    float t = up[k] + v[q + k];
                    t = fmaf(d[r], wv[q + k], t);
                    acc[r] = fmaf(__builtin_fabsf(t), fv[q + k], acc[r]);
                }
            }
        }
    }

    // epilogue: rank-1 linear half + bias, coalesced stores
    if (j < NN) {
        const float c = cptr[0];
        const float b2 = fc2b[0];
        const float Bj = Bcol[jc];
        #pragma unroll
        for (int r = 0; r < IB; ++r) {
            float lin = Arow[i0 + r] + Bj + d[r] * c;
            out[(size_t)(i0 + r) * NN + j] = fmaf(0.5f, lin + acc[r], b2);
        }
    }
}

// ---------------------------------------------------------------------------
extern "C" void kernel_launch(void* const* d_in, const int* in_sizes, int n_in,
                              void* d_out, int out_size, void* d_ws, size_t ws_size,
                              hipStream_t stream) {
    const float* geo  = (const float*)d_in[0];
    const float* sem  = (const float*)d_in[1];
    const float* feat = (const float*)d_in[2];
    // d_in[3] = region_pairs: full meshgrid -> row-major (i,j); unused
    const float* dist = (const float*)d_in[4];
    const float* W0   = (const float*)d_in[5];
    const float* W1   = (const float*)d_in[6];
    const float* W2   = (const float*)d_in[7];
    const float* a0   = (const float*)d_in[8];
    const float* a1   = (const float*)d_in[9];
    const float* a2   = (const float*)d_in[10];
    const float* fc1w = (const float*)d_in[11];
    const float* fc1b = (const float*)d_in[12];
    const float* fc2w = (const float*)d_in[13];
    const float* fc2b = (const float*)d_in[14];
    float* out = (float*)d_out;

    // workspace layout (~4.2 MB); all chunk sizes keep 16B alignment
    char* ws = (char*)d_ws;
    int*   csr_idx = (int*)ws;                         ws += sizeof(int) * NN * CAP;
    float* csr_val = (float*)ws;                       ws += sizeof(float) * NN * CAP;
    int*   csr_cnt = (int*)ws;                         ws += sizeof(int) * NN;
    float* encA    = (float*)ws;                       ws += sizeof(float) * NN * GOUT;
    float* encB    = (float*)ws;                       ws += sizeof(float) * NN * GOUT;
    float* Ubuf    = (float*)ws;                       ws += sizeof(float) * NN * HID;
    float* Vbuf    = (float*)ws;                       ws += sizeof(float) * NN * HID;
    float* Ar      = (float*)ws;                       ws += sizeof(float) * NN;
    float* Bc      = (float*)ws;                       ws += sizeof(float) * NN;
    float* cptr    = (float*)ws;

    gat_first<<<NN, 256, 0, stream>>>(geo, sem, feat, W0, a0,
                                      csr_idx, csr_val, csr_cnt, encA);
    gat_layer<GOUT, false><<<NN / 4, 256, 0, stream>>>(
        encA, W1, a1, csr_idx, csr_val, csr_cnt, encB,
        nullptr, nullptr, nullptr, nullptr, nullptr, nullptr, nullptr, nullptr);
    gat_layer<GOUT, true><<<NN / 4, 256, 0, stream>>>(
        encB, W2, a2, csr_idx, csr_val, csr_cnt, encA,
        fc1w, fc1b, fc2w, Ubuf, Vbuf, Ar, Bc, cptr);

    dim3 mg((NN + 255) / 256, (NN + IB - 1) / IB);   // 6 x 125
    mlp_kernel<<<mg, 256, 0, stream>>>(Ubuf, Vbuf, Ar, Bc, cptr,
                                       dist, fc1w, fc2w, fc2b, out);
}

// Round 9
// 155.091 us; speedup vs baseline: 1.0936x; 1.0114x over previous
//
#include <hip/hip_runtime.h>
#include <hip/hip_bf16.h>

#define NN 1500
#define GIN 32
#define GOUT 8
#define HID 128
#define CAP 192           // max nnz/row kept; mean ~60, sigma ~7.6 -> 17 sigma headroom

// ---------------------------------------------------------------------------
// Fused: compact combined adjacency row (geo+sem > 0) into LDS, write CSR for
// layers 2-3, and compute GAT layer 1 attention for this row in one kernel.
// One block (256 thr) per row.
// ---------------------------------------------------------------------------
__global__ void gat_first(const float* __restrict__ geo,
                          const float* __restrict__ sem,
                          const float* __restrict__ feat,   // NN x 32
                          const float* __restrict__ W0,     // 32 x 8
                          const float* __restrict__ a0,     // 16
                          int* __restrict__ csr_idx,
                          float* __restrict__ csr_val,
                          int* __restrict__ csr_cnt,
                          float* __restrict__ enc_out) {
    const int i = blockIdx.x;
    const int t = threadIdx.x;  // 256
    __shared__ int cnt;
    __shared__ int sidx[CAP];
    __shared__ float sval[CAP];
    __shared__ float hi_s[GOUT];
    __shared__ float wsum[4][GOUT + 1];
    if (t == 0) cnt = 0;
    __syncthreads();

    const float* grow = geo + (size_t)i * NN;
    const float* srow = sem + (size_t)i * NN;
    for (int q = t; q < NN / 4; q += 256) {
        float4 g = *(const float4*)(grow + 4 * q);
        float4 s = *(const float4*)(srow + 4 * q);
        float a[4] = {g.x + s.x, g.y + s.y, g.z + s.z, g.w + s.w};
        #pragma unroll
        for (int c = 0; c < 4; ++c) {
            if (a[c] > 0.f) {
                int p = atomicAdd(&cnt, 1);
                if (p < CAP) { sidx[p] = 4 * q + c; sval[p] = a[c]; }
            }
        }
    }
    // h_i (only needed for f_src): threads 0..7
    if (t < GOUT) {
        float hv = 0.f;
        #pragma unroll 4
        for (int c = 0; c < GIN; ++c)
            hv = fmaf(feat[(size_t)i * GIN + c], W0[c * GOUT + t], hv);
        hi_s[t] = hv;
    }
    __syncthreads();

    const int c2 = cnt < CAP ? cnt : CAP;
    if (t == 0) csr_cnt[i] = c2;
    for (int p = t; p < c2; p += 256) {
        csr_idx[(size_t)i * CAP + p] = sidx[p];
        csr_val[(size_t)i * CAP + p] = sval[p];
    }
    float fsrc = 0.f;
    #pragma unroll
    for (int k = 0; k < GOUT; ++k) fsrc = fmaf(hi_s[k], a0[k], fsrc);

    // attention: one entry per thread (cnt <= 192 < 256 -> single pass)
    float den = 0.f;
    float num[GOUT] = {};
    if (t < c2) {
        int j = sidx[t];
        float a = sval[t];
        float hj[GOUT] = {};
        #pragma unroll
        for (int c4 = 0; c4 < GIN / 4; ++c4) {
            float4 e4 = *(const float4*)(feat + (size_t)j * GIN + 4 * c4);
            const float* ep = (const float*)&e4;
            #pragma unroll
            for (int c = 0; c < 4; ++c)
                #pragma unroll
                for (int k = 0; k < GOUT; ++k)
                    hj[k] = fmaf(ep[c], W0[(4 * c4 + c) * GOUT + k], hj[k]);
        }
        float fd = 0.f;
        #pragma unroll
        for (int k = 0; k < GOUT; ++k) fd = fmaf(hj[k], a0[GOUT + k], fd);
        float ev = fsrc + fd;
        ev = (ev > 0.f) ? ev : 0.2f * ev;
        ev *= a;
        float p = __expf(ev);
        den = p;
        #pragma unroll
        for (int k = 0; k < GOUT; ++k) num[k] = p * hj[k];
    }
    #pragma unroll
    for (int off = 32; off > 0; off >>= 1) {
        den += __shfl_xor(den, off, 64);
        #pragma unroll
        for (int k = 0; k < GOUT; ++k) num[k] += __shfl_xor(num[k], off, 64);
    }
    if ((t & 63) == 0) {
        wsum[t >> 6][0] = den;
        #pragma unroll
        for (int k = 0; k < GOUT; ++k) wsum[t >> 6][1 + k] = num[k];
    }
    __syncthreads();
    if (t < GOUT) {
        float L = wsum[0][0] + wsum[1][0] + wsum[2][0] + wsum[3][0];
        float v = (wsum[0][1 + t] + wsum[1][1 + t] + wsum[2][1 + t] + wsum[3][1 + t]) / L;
        enc_out[(size_t)i * GOUT + t] = (v > 0.f) ? v : (__expf(v) - 1.f);
    }
}

// ---------------------------------------------------------------------------
// GAT layers 2,3: one WAVE per row i, CSR-driven. When UV=true (layer 3),
// the wave also computes U[i,:], V[i,:], A[i]=sum_k U*f2, B[i]=sum_k V*f2
// (rank-1 split of the MLP), and row 0's wave writes c = sum_k w16[k]*f2[k].
// ---------------------------------------------------------------------------
template<int IN, bool UV>
__global__ void gat_layer(const float* __restrict__ enc,
                          const float* __restrict__ W,     // IN x 8
                          const float* __restrict__ avec,  // 16
                          const int* __restrict__ csr_idx,
                          const float* __restrict__ csr_val,
                          const int* __restrict__ csr_cnt,
                          float* __restrict__ enc_out,
                          const float* __restrict__ fc1w,  // 17 x 128
                          const float* __restrict__ fc1b,  // 128
                          const float* __restrict__ fc2w,  // 128
                          float* __restrict__ Ubuf, float* __restrict__ Vbuf,
                          float* __restrict__ Arow, float* __restrict__ Bcol,
                          float* __restrict__ cptr) {
    const int tid = threadIdx.x;            // 256 = 4 waves, 1 wave per row
    const int lane = tid & 63;
    const int i = blockIdx.x * 4 + (tid >> 6);   // 375*4 == 1500 exact

    float hv = 0.f;
    if (lane < GOUT) {
        #pragma unroll 4
        for (int c = 0; c < IN; ++c)
            hv = fmaf(enc[(size_t)i * IN + c], W[c * GOUT + lane], hv);
    }
    float hi[GOUT];
    #pragma unroll
    for (int c = 0; c < GOUT; ++c) hi[c] = __shfl(hv, c, 64);
    float fsrc = 0.f;
    #pragma unroll
    for (int c = 0; c < GOUT; ++c) fsrc = fmaf(hi[c], avec[c], fsrc);

    const int cnt = csr_cnt[i];
    float den = 0.f;
    float num[GOUT] = {};
    for (int e = lane; e < cnt; e += 64) {
        int j = csr_idx[(size_t)i * CAP + e];
        float a = csr_val[(size_t)i * CAP + e];
        float hj[GOUT] = {};
        #pragma unroll
        for (int c4 = 0; c4 < IN / 4; ++c4) {
            float4 e4 = *(const float4*)(enc + (size_t)j * IN + 4 * c4);
            const float* ep = (const float*)&e4;
            #pragma unroll
            for (int c = 0; c < 4; ++c)
                #pragma unroll
                for (int k = 0; k < GOUT; ++k)
                    hj[k] = fmaf(ep[c], W[(4 * c4 + c) * GOUT + k], hj[k]);
        }
        float fd = 0.f;
        #pragma unroll
        for (int k = 0; k < GOUT; ++k) fd = fmaf(hj[k], avec[GOUT + k], fd);
        float ev = fsrc + fd;
        ev = (ev > 0.f) ? ev : 0.2f * ev;
        ev *= a;
        float p = __expf(ev);
        den += p;
        #pragma unroll
        for (int k = 0; k < GOUT; ++k) num[k] = fmaf(p, hj[k], num[k]);
    }
    #pragma unroll
    for (int off = 32; off > 0; off >>= 1) {
        den += __shfl_xor(den, off, 64);
        #pragma unroll
        for (int k = 0; k < GOUT; ++k) num[k] += __shfl_xor(num[k], off, 64);
    }
    // elu output for this row (valid at lanes 0..7)
    float vout = 0.f;
    if (lane < GOUT) {
        float v = num[lane] / den;
        vout = (v > 0.f) ? v : (__expf(v) - 1.f);
        enc_out[(size_t)i * GOUT + lane] = vout;
    }

    if constexpr (UV) {
        float er[GOUT];
        #pragma unroll
        for (int c = 0; c < GOUT; ++c) er[c] = __shfl(vout, c, 64);
        const int kl = lane, kh = lane + 64;
        float u_lo = fc1b[kl], u_hi = fc1b[kh];
        float v_lo = 0.f, v_hi = 0.f;
        #pragma unroll
        for (int c = 0; c < GOUT; ++c) {
            u_lo = fmaf(er[c], fc1w[c * HID + kl], u_lo);
            u_hi = fmaf(er[c], fc1w[c * HID + kh], u_hi);
            v_lo = fmaf(er[c], fc1w[(GOUT + c) * HID + kl], v_lo);
            v_hi = fmaf(er[c], fc1w[(GOUT + c) * HID + kh], v_hi);
        }
        Ubuf[(size_t)i * HID + kl] = u_lo;
        Ubuf[(size_t)i * HID + kh] = u_hi;
        Vbuf[(size_t)i * HID + kl] = v_lo;
        Vbuf[(size_t)i * HID + kh] = v_hi;
        const float f_lo = fc2w[kl], f_hi = fc2w[kh];
        float ap = u_lo * f_lo + u_hi * f_hi;
        float bp = v_lo * f_lo + v_hi * f_hi;
        #pragma unroll
        for (int off = 32; off > 0; off >>= 1) {
            ap += __shfl_xor(ap, off, 64);
            bp += __shfl_xor(bp, off, 64);
        }
        if (lane == 0) { Arow[i] = ap; Bcol[i] = bp; }
        if (i == 0) {
            const float* w16g = fc1w + 2 * GOUT * HID;
            float cp = w16g[kl] * f_lo + w16g[kh] * f_hi;
            #pragma unroll
            for (int off = 32; off > 0; off >>= 1) cp += __shfl_xor(cp, off, 64);
            if (lane == 0) cptr[0] = cp;
        }
    }
}

// ---------------------------------------------------------------------------
// Pair-MLP, LDS-free (R8 structure), occupancy doubled:
//   IB 12 -> 6, grid 6 x 250 = 1500 blocks = 6000 waves ~ 5.9/SIMD (2x R8).
// R8 post-mortem: VALU issue efficiency has tracked resident waves/SIMD across
// R4-R8 (never above ~3/SIMD); total VALU work is occupancy-invariant here, so
// doubling waves should close most of the s_load/VMEM latency bubbles.
//   lane = column j; V[j,k],d[i,j] per-lane VGPR; U/w16/f2 wave-uniform s_load.
//   out = fc2b + 0.5*(A_i + B_j + d*c) + 0.5*sum_k |U+V+d*w16|*f2  (relu->abs)
// 3 VALU/k/output, no LDS, no barriers, no atomics, coalesced stores.
// ---------------------------------------------------------------------------
#define IB 6
#define KC 16

__global__ __launch_bounds__(256, 6) void mlp_kernel(
        const float* __restrict__ U, const float* __restrict__ V,
        const float* __restrict__ Arow, const float* __restrict__ Bcol,
        const float* __restrict__ cptr,
        const float* __restrict__ dist,
        const float* __restrict__ fc1w,   // 17 x 128 (row 16 = w16)
        const float* __restrict__ fc2w,   // 128
        const float* __restrict__ fc2b,   // 1
        float* __restrict__ out) {
    const int tid = threadIdx.x;
    const int j = blockIdx.x * 256 + tid;        // 6*256 = 1536 covers 1500
    const int jc = j < NN ? j : NN - 1;
    const int i0 = blockIdx.y * IB;              // 250*6 = 1500 exact
    const float* w16g = fc1w + 2 * GOUT * HID;

    // distance column strip + accumulators (per-lane registers)
    float d[IB], acc[IB];
    #pragma unroll
    for (int r = 0; r < IB; ++r) {
        d[r] = dist[(size_t)(i0 + r) * NN + jc];
        acc[r] = 0.f;
    }

    const float* Vrow = V + (size_t)jc * HID;
    for (int kc = 0; kc < HID; kc += KC) {   // 8 chunks
        // per-lane V chunk
        float v[KC];
        #pragma unroll
        for (int q = 0; q < KC; q += 4)
            *(float4*)(v + q) = *(const float4*)(Vrow + kc + q);
        // wave-uniform chunks -> SGPRs
        float wv[KC], fv[KC];
        #pragma unroll
        for (int q = 0; q < KC; q += 4) {
            *(float4*)(wv + q) = *(const float4*)(w16g + kc + q);
            *(float4*)(fv + q) = *(const float4*)(fc2w + kc + q);
        }
        #pragma unroll
        for (int r = 0; r < IB; ++r) {
            const float* Urow = U + (size_t)(i0 + r) * HID + kc;  // uniform
            #pragma unroll
            for (int q = 0; q < KC; q += 4) {
                float4 u4 = *(const float4*)(Urow + q);           // s_load x4
                const float* up = (const float*)&u4;
                #pragma unroll
                for (int k = 0; k < 4; ++k) {
                    float t = up[k] + v[q + k];
                    t = fmaf(d[r], wv[q + k], t);
                    acc[r] = fmaf(__builtin_fabsf(t), fv[q + k], acc[r]);
                }
            }
        }
    }

    // epilogue: rank-1 linear half + bias, coalesced stores
    if (j < NN) {
        const float c = cptr[0];
        const float b2 = fc2b[0];
        const float Bj = Bcol[jc];
        #pragma unroll
        for (int r = 0; r < IB; ++r) {
            float lin = Arow[i0 + r] + Bj + d[r] * c;
            out[(size_t)(i0 + r) * NN + j] = fmaf(0.5f, lin + acc[r], b2);
        }
    }
}

// ---------------------------------------------------------------------------
extern "C" void kernel_launch(void* const* d_in, const int* in_sizes, int n_in,
                              void* d_out, int out_size, void* d_ws, size_t ws_size,
                              hipStream_t stream) {
    const float* geo  = (const float*)d_in[0];
    const float* sem  = (const float*)d_in[1];
    const float* feat = (const float*)d_in[2];
    // d_in[3] = region_pairs: full meshgrid -> row-major (i,j); unused
    const float* dist = (const float*)d_in[4];
    const float* W0   = (const float*)d_in[5];
    const float* W1   = (const float*)d_in[6];
    const float* W2   = (const float*)d_in[7];
    const float* a0   = (const float*)d_in[8];
    const float* a1   = (const float*)d_in[9];
    const float* a2   = (const float*)d_in[10];
    const float* fc1w = (const float*)d_in[11];
    const float* fc1b = (const float*)d_in[12];
    const float* fc2w = (const float*)d_in[13];
    const float* fc2b = (const float*)d_in[14];
    float* out = (float*)d_out;

    // workspace layout (~4.2 MB); all chunk sizes keep 16B alignment
    char* ws = (char*)d_ws;
    int*   csr_idx = (int*)ws;                         ws += sizeof(int) * NN * CAP;
    float* csr_val = (float*)ws;                       ws += sizeof(float) * NN * CAP;
    int*   csr_cnt = (int*)ws;                         ws += sizeof(int) * NN;
    float* encA    = (float*)ws;                       ws += sizeof(float) * NN * GOUT;
    float* encB    = (float*)ws;                       ws += sizeof(float) * NN * GOUT;
    float* Ubuf    = (float*)ws;                       ws += sizeof(float) * NN * HID;
    float* Vbuf    = (float*)ws;                       ws += sizeof(float) * NN * HID;
    float* Ar      = (float*)ws;                       ws += sizeof(float) * NN;
    float* Bc      = (float*)ws;                       ws += sizeof(float) * NN;
    float* cptr    = (float*)ws;

    gat_first<<<NN, 256, 0, stream>>>(geo, sem, feat, W0, a0,
                                      csr_idx, csr_val, csr_cnt, encA);
    gat_layer<GOUT, false><<<NN / 4, 256, 0, stream>>>(
        encA, W1, a1, csr_idx, csr_val, csr_cnt, encB,
        nullptr, nullptr, nullptr, nullptr, nullptr, nullptr, nullptr, nullptr);
    gat_layer<GOUT, true><<<NN / 4, 256, 0, stream>>>(
        encB, W2, a2, csr_idx, csr_val, csr_cnt, encA,
        fc1w, fc1b, fc2w, Ubuf, Vbuf, Ar, Bc, cptr);

    dim3 mg((NN + 255) / 256, (NN + IB - 1) / IB);   // 6 x 250
    mlp_kernel<<<mg, 256, 0, stream>>>(Ubuf, Vbuf, Ar, Bc, cptr,
                                       dist, fc1w, fc2w, fc2b, out);
}

// Round 10
// 149.066 us; speedup vs baseline: 1.1378x; 1.0404x over previous
//
#include <hip/hip_runtime.h>
#include <hip/hip_bf16.h>

#define NN 1500
#define GIN 32
#define GOUT 8
#define HID 128
#define CAP 192           // max nnz/row kept; mean ~60, sigma ~7.6 -> 17 sigma headroom

typedef _Float16 h2 __attribute__((ext_vector_type(2)));

__device__ __forceinline__ h2 u2h(unsigned int x) { return __builtin_bit_cast(h2, x); }
__device__ __forceinline__ unsigned int h2u(h2 x) { return __builtin_bit_cast(unsigned int, x); }

// ---------------------------------------------------------------------------
// Fused: compact combined adjacency row (geo+sem > 0) into LDS, write CSR for
// layers 2-3, and compute GAT layer 1 attention for this row in one kernel.
// One block (256 thr) per row.
// ---------------------------------------------------------------------------
__global__ void gat_first(const float* __restrict__ geo,
                          const float* __restrict__ sem,
                          const float* __restrict__ feat,   // NN x 32
                          const float* __restrict__ W0,     // 32 x 8
                          const float* __restrict__ a0,     // 16
                          int* __restrict__ csr_idx,
                          float* __restrict__ csr_val,
                          int* __restrict__ csr_cnt,
                          float* __restrict__ enc_out) {
    const int i = blockIdx.x;
    const int t = threadIdx.x;  // 256
    __shared__ int cnt;
    __shared__ int sidx[CAP];
    __shared__ float sval[CAP];
    __shared__ float hi_s[GOUT];
    __shared__ float wsum[4][GOUT + 1];
    if (t == 0) cnt = 0;
    __syncthreads();

    const float* grow = geo + (size_t)i * NN;
    const float* srow = sem + (size_t)i * NN;
    for (int q = t; q < NN / 4; q += 256) {
        float4 g = *(const float4*)(grow + 4 * q);
        float4 s = *(const float4*)(srow + 4 * q);
        float a[4] = {g.x + s.x, g.y + s.y, g.z + s.z, g.w + s.w};
        #pragma unroll
        for (int c = 0; c < 4; ++c) {
            if (a[c] > 0.f) {
                int p = atomicAdd(&cnt, 1);
                if (p < CAP) { sidx[p] = 4 * q + c; sval[p] = a[c]; }
            }
        }
    }
    // h_i (only needed for f_src): threads 0..7
    if (t < GOUT) {
        float hv = 0.f;
        #pragma unroll 4
        for (int c = 0; c < GIN; ++c)
            hv = fmaf(feat[(size_t)i * GIN + c], W0[c * GOUT + t], hv);
        hi_s[t] = hv;
    }
    __syncthreads();

    const int c2 = cnt < CAP ? cnt : CAP;
    if (t == 0) csr_cnt[i] = c2;
    for (int p = t; p < c2; p += 256) {
        csr_idx[(size_t)i * CAP + p] = sidx[p];
        csr_val[(size_t)i * CAP + p] = sval[p];
    }
    float fsrc = 0.f;
    #pragma unroll
    for (int k = 0; k < GOUT; ++k) fsrc = fmaf(hi_s[k], a0[k], fsrc);

    // attention: one entry per thread (cnt <= 192 < 256 -> single pass)
    float den = 0.f;
    float num[GOUT] = {};
    if (t < c2) {
        int j = sidx[t];
        float a = sval[t];
        float hj[GOUT] = {};
        #pragma unroll
        for (int c4 = 0; c4 < GIN / 4; ++c4) {
            float4 e4 = *(const float4*)(feat + (size_t)j * GIN + 4 * c4);
            const float* ep = (const float*)&e4;
            #pragma unroll
            for (int c = 0; c < 4; ++c)
                #pragma unroll
                for (int k = 0; k < GOUT; ++k)
                    hj[k] = fmaf(ep[c], W0[(4 * c4 + c) * GOUT + k], hj[k]);
        }
        float fd = 0.f;
        #pragma unroll
        for (int k = 0; k < GOUT; ++k) fd = fmaf(hj[k], a0[GOUT + k], fd);
        float ev = fsrc + fd;
        ev = (ev > 0.f) ? ev : 0.2f * ev;
        ev *= a;
        float p = __expf(ev);
        den = p;
        #pragma unroll
        for (int k = 0; k < GOUT; ++k) num[k] = p * hj[k];
    }
    #pragma unroll
    for (int off = 32; off > 0; off >>= 1) {
        den += __shfl_xor(den, off, 64);
        #pragma unroll
        for (int k = 0; k < GOUT; ++k) num[k] += __shfl_xor(num[k], off, 64);
    }
    if ((t & 63) == 0) {
        wsum[t >> 6][0] = den;
        #pragma unroll
        for (int k = 0; k < GOUT; ++k) wsum[t >> 6][1 + k] = num[k];
    }
    __syncthreads();
    if (t < GOUT) {
        float L = wsum[0][0] + wsum[1][0] + wsum[2][0] + wsum[3][0];
        float v = (wsum[0][1 + t] + wsum[1][1 + t] + wsum[2][1 + t] + wsum[3][1 + t]) / L;
        enc_out[(size_t)i * GOUT + t] = (v > 0.f) ? v : (__expf(v) - 1.f);
    }
}

// ---------------------------------------------------------------------------
// GAT layers 2,3: one WAVE per row i, CSR-driven. When UV=true (layer 3),
// the wave also computes U[i,:], V[i,:] (stored as f16 for the packed-math
// MLP), A[i]=sum_k U*f2, B[i]=sum_k V*f2 (fp32 rank-1 split), and row 0's
// wave writes c = sum_k w16*f2 plus f16 copies of w16 and fc2w.
// ---------------------------------------------------------------------------
template<int IN, bool UV>
__global__ void gat_layer(const float* __restrict__ enc,
                          const float* __restrict__ W,     // IN x 8
                          const float* __restrict__ avec,  // 16
                          const int* __restrict__ csr_idx,
                          const float* __restrict__ csr_val,
                          const int* __restrict__ csr_cnt,
                          float* __restrict__ enc_out,
                          const float* __restrict__ fc1w,  // 17 x 128
                          const float* __restrict__ fc1b,  // 128
                          const float* __restrict__ fc2w,  // 128
                          _Float16* __restrict__ Uh, _Float16* __restrict__ Vh,
                          _Float16* __restrict__ wh, _Float16* __restrict__ fh,
                          float* __restrict__ Arow, float* __restrict__ Bcol,
                          float* __restrict__ cptr) {
    const int tid = threadIdx.x;            // 256 = 4 waves, 1 wave per row
    const int lane = tid & 63;
    const int i = blockIdx.x * 4 + (tid >> 6);   // 375*4 == 1500 exact

    float hv = 0.f;
    if (lane < GOUT) {
        #pragma unroll 4
        for (int c = 0; c < IN; ++c)
            hv = fmaf(enc[(size_t)i * IN + c], W[c * GOUT + lane], hv);
    }
    float hi[GOUT];
    #pragma unroll
    for (int c = 0; c < GOUT; ++c) hi[c] = __shfl(hv, c, 64);
    float fsrc = 0.f;
    #pragma unroll
    for (int c = 0; c < GOUT; ++c) fsrc = fmaf(hi[c], avec[c], fsrc);

    const int cnt = csr_cnt[i];
    float den = 0.f;
    float num[GOUT] = {};
    for (int e = lane; e < cnt; e += 64) {
        int j = csr_idx[(size_t)i * CAP + e];
        float a = csr_val[(size_t)i * CAP + e];
        float hj[GOUT] = {};
        #pragma unroll
        for (int c4 = 0; c4 < IN / 4; ++c4) {
            float4 e4 = *(const float4*)(enc + (size_t)j * IN + 4 * c4);
            const float* ep = (const float*)&e4;
            #pragma unroll
            for (int c = 0; c < 4; ++c)
                #pragma unroll
                for (int k = 0; k < GOUT; ++k)
                    hj[k] = fmaf(ep[c], W[(4 * c4 + c) * GOUT + k], hj[k]);
        }
        float fd = 0.f;
        #pragma unroll
        for (int k = 0; k < GOUT; ++k) fd = fmaf(hj[k], avec[GOUT + k], fd);
        float ev = fsrc + fd;
        ev = (ev > 0.f) ? ev : 0.2f * ev;
        ev *= a;
        float p = __expf(ev);
        den += p;
        #pragma unroll
        for (int k = 0; k < GOUT; ++k) num[k] = fmaf(p, hj[k], num[k]);
    }
    #pragma unroll
    for (int off = 32; off > 0; off >>= 1) {
        den += __shfl_xor(den, off, 64);
        #pragma unroll
        for (int k = 0; k < GOUT; ++k) num[k] += __shfl_xor(num[k], off, 64);
    }
    // elu output for this row (valid at lanes 0..7)
    float vout = 0.f;
    if (lane < GOUT) {
        float v = num[lane] / den;
        vout = (v > 0.f) ? v : (__expf(v) - 1.f);
        enc_out[(size_t)i * GOUT + lane] = vout;
    }

    if constexpr (UV) {
        float er[GOUT];
        #pragma unroll
        for (int c = 0; c < GOUT; ++c) er[c] = __shfl(vout, c, 64);
        const int kl = lane, kh = lane + 64;
        float u_lo = fc1b[kl], u_hi = fc1b[kh];
        float v_lo = 0.f, v_hi = 0.f;
        #pragma unroll
        for (int c = 0; c < GOUT; ++c) {
            u_lo = fmaf(er[c], fc1w[c * HID + kl], u_lo);
            u_hi = fmaf(er[c], fc1w[c * HID + kh], u_hi);
            v_lo = fmaf(er[c], fc1w[(GOUT + c) * HID + kl], v_lo);
            v_hi = fmaf(er[c], fc1w[(GOUT + c) * HID + kh], v_hi);
        }
        Uh[(size_t)i * HID + kl] = (_Float16)u_lo;
        Uh[(size_t)i * HID + kh] = (_Float16)u_hi;
        Vh[(size_t)i * HID + kl] = (_Float16)v_lo;
        Vh[(size_t)i * HID + kh] = (_Float16)v_hi;
        const float f_lo = fc2w[kl], f_hi = fc2w[kh];
        float ap = u_lo * f_lo + u_hi * f_hi;
        float bp = v_lo * f_lo + v_hi * f_hi;
        #pragma unroll
        for (int off = 32; off > 0; off >>= 1) {
            ap += __shfl_xor(ap, off, 64);
            bp += __shfl_xor(bp, off, 64);
        }
        if (lane == 0) { Arow[i] = ap; Bcol[i] = bp; }
        if (i == 0) {
            const float* w16g = fc1w + 2 * GOUT * HID;
            wh[kl] = (_Float16)w16g[kl];
            wh[kh] = (_Float16)w16g[kh];
            fh[kl] = (_Float16)f_lo;
            fh[kh] = (_Float16)f_hi;
            float cp = w16g[kl] * f_lo + w16g[kh] * f_hi;
            #pragma unroll
            for (int off = 32; off > 0; off >>= 1) cp += __shfl_xor(cp, off, 64);
            if (lane == 0) cptr[0] = cp;
        }
    }
}

// ---------------------------------------------------------------------------
// Pair-MLP, LDS-free lane=j structure (R8), inner loop in PACKED f16:
//   per 2 k: v_pk_add_f16 (t=u+v), v_pk_fma_f16 (t+=d*w16),
//            v_and_b32 (|t| both halves), v_dot2_f32_f16 (fp32 acc += |t|.f2)
// -> 2 inst/k vs R9's 3 inst/k (R9 post-mortem: issue-bound; occupancy-
// and structure-invariant at ~45% VALUBusy, so cut the instruction count).
// Accumulation and the rank-1 linear half stay fp32; only t is f16.
//   out = fc2b + 0.5*(A_i + B_j + d*c) + 0.5*sum_k |U+V+d*w16|*f2  (relu->abs)
// Grid 6 x 250 = 1500 blocks = ~5.9 waves/SIMD; ~45 VGPR.
// ---------------------------------------------------------------------------
#define IB 6

__global__ __launch_bounds__(256, 6) void mlp_kernel(
        const _Float16* __restrict__ Uh, const _Float16* __restrict__ Vh,
        const _Float16* __restrict__ wh, const _Float16* __restrict__ fh,
        const float* __restrict__ Arow, const float* __restrict__ Bcol,
        const float* __restrict__ cptr,
        const float* __restrict__ dist,
        const float* __restrict__ fc2b,   // 1
        float* __restrict__ out) {
    const int tid = threadIdx.x;
    const int j = blockIdx.x * 256 + tid;        // 6*256 = 1536 covers 1500
    const int jc = j < NN ? j : NN - 1;
    const int i0 = blockIdx.y * IB;              // 250*6 = 1500 exact

    // distance strip (fp32 for epilogue + f16-pair splat for the inner fma)
    float d[IB], acc[IB];
    h2 d2[IB];
    #pragma unroll
    for (int r = 0; r < IB; ++r) {
        d[r] = dist[(size_t)(i0 + r) * NN + jc];
        acc[r] = 0.f;
        _Float16 dh = (_Float16)d[r];
        d2[r] = h2{dh, dh};
    }

    const uint4* Vrow = (const uint4*)(Vh + (size_t)jc * HID);  // 16 x uint4
    const uint4* Wt = (const uint4*)wh;
    const uint4* Ft = (const uint4*)fh;

    for (int c4 = 0; c4 < 4; ++c4) {    // 4 chunks of 32 k (8 halves/uint4)
        uint4 vv[4], ww[4], ff[4];
        #pragma unroll
        for (int q = 0; q < 4; ++q) {
            vv[q] = Vrow[c4 * 4 + q];   // per-lane VMEM
            ww[q] = Wt[c4 * 4 + q];     // wave-uniform -> s_load
            ff[q] = Ft[c4 * 4 + q];
        }
        #pragma unroll
        for (int r = 0; r < IB; ++r) {
            const uint4* Urow = (const uint4*)(Uh + (size_t)(i0 + r) * HID) + c4 * 4;
            #pragma unroll
            for (int q = 0; q < 4; ++q) {
                uint4 uu = Urow[q];     // wave-uniform -> s_load
                const unsigned int ue[4] = {uu.x, uu.y, uu.z, uu.w};
                const unsigned int ve[4] = {vv[q].x, vv[q].y, vv[q].z, vv[q].w};
                const unsigned int we[4] = {ww[q].x, ww[q].y, ww[q].z, ww[q].w};
                const unsigned int fe[4] = {ff[q].x, ff[q].y, ff[q].z, ff[q].w};
                #pragma unroll
                for (int e = 0; e < 4; ++e) {
                    h2 t = u2h(ue[e]) + u2h(ve[e]);                       // v_pk_add_f16
                    t = __builtin_elementwise_fma(d2[r], u2h(we[e]), t);  // v_pk_fma_f16
                    t = u2h(h2u(t) & 0x7fff7fffu);                        // |.| both halves
                    acc[r] = __builtin_amdgcn_fdot2(t, u2h(fe[e]), acc[r], false);
                }
            }
        }
    }

    // epilogue: fp32 rank-1 linear half + bias, coalesced stores
    if (j < NN) {
        const float c = cptr[0];
        const float b2 = fc2b[0];
        const float Bj = Bcol[jc];
        #pragma unroll
        for (int r = 0; r < IB; ++r) {
            float lin = Arow[i0 + r] + Bj + d[r] * c;
            out[(size_t)(i0 + r) * NN + j] = fmaf(0.5f, lin + acc[r], b2);
        }
    }
}

// ---------------------------------------------------------------------------
extern "C" void kernel_launch(void* const* d_in, const int* in_sizes, int n_in,
                              void* d_out, int out_size, void* d_ws, size_t ws_size,
                              hipStream_t stream) {
    const float* geo  = (const float*)d_in[0];
    const float* sem  = (const float*)d_in[1];
    const float* feat = (const float*)d_in[2];
    // d_in[3] = region_pairs: full meshgrid -> row-major (i,j); unused
    const float* dist = (const float*)d_in[4];
    const float* W0   = (const float*)d_in[5];
    const float* W1   = (const float*)d_in[6];
    const float* W2   = (const float*)d_in[7];
    const float* a0   = (const float*)d_in[8];
    const float* a1   = (const float*)d_in[9];
    const float* a2   = (const float*)d_in[10];
    const float* fc1w = (const float*)d_in[11];
    const float* fc1b = (const float*)d_in[12];
    const float* fc2w = (const float*)d_in[13];
    const float* fc2b = (const float*)d_in[14];
    float* out = (float*)d_out;

    // workspace layout (~3.5 MB); all chunk sizes keep 16B alignment
    char* ws = (char*)d_ws;
    int*      csr_idx = (int*)ws;                     ws += sizeof(int) * NN * CAP;
    float*    csr_val = (float*)ws;                   ws += sizeof(float) * NN * CAP;
    int*      csr_cnt = (int*)ws;                     ws += sizeof(int) * NN;
    float*    encA    = (float*)ws;                   ws += sizeof(float) * NN * GOUT;
    float*    encB    = (float*)ws;                   ws += sizeof(float) * NN * GOUT;
    _Float16* Uh      = (_Float16*)ws;                ws += sizeof(_Float16) * NN * HID;
    _Float16* Vh      = (_Float16*)ws;                ws += sizeof(_Float16) * NN * HID;
    _Float16* wh      = (_Float16*)ws;                ws += sizeof(_Float16) * HID;
    _Float16* fh      = (_Float16*)ws;                ws += sizeof(_Float16) * HID;
    float*    Ar      = (float*)ws;                   ws += sizeof(float) * NN;
    float*    Bc      = (float*)ws;                   ws += sizeof(float) * NN;
    float*    cptr    = (float*)ws;

    gat_first<<<NN, 256, 0, stream>>>(geo, sem, feat, W0, a0,
                                      csr_idx, csr_val, csr_cnt, encA);
    gat_layer<GOUT, false><<<NN / 4, 256, 0, stream>>>(
        encA, W1, a1, csr_idx, csr_val, csr_cnt, encB,
        nullptr, nullptr, nullptr,
        nullptr, nullptr, nullptr, nullptr, nullptr, nullptr, nullptr);
    gat_layer<GOUT, true><<<NN / 4, 256, 0, stream>>>(
        encB, W2, a2, csr_idx, csr_val, csr_cnt, encA,
        fc1w, fc1b, fc2w, Uh, Vh, wh, fh, Ar, Bc, cptr);

    dim3 mg((NN + 255) / 256, (NN + IB - 1) / IB);   // 6 x 250
    mlp_kernel<<<mg, 256, 0, stream>>>(Uh, Vh, wh, fh, Ar, Bc, cptr,
                                       dist, fc2b, out);
}

// Round 11
// 146.587 us; speedup vs baseline: 1.1571x; 1.0169x over previous
//
#include <hip/hip_runtime.h>
#include <hip/hip_bf16.h>

#define NN 1500
#define GIN 32
#define GOUT 8
#define HID 128
#define CAP 192           // max nnz/row kept; mean ~60, sigma ~7.6 -> 17 sigma headroom

typedef _Float16 h2 __attribute__((ext_vector_type(2)));

__device__ __forceinline__ h2 u2h(unsigned int x) { return __builtin_bit_cast(h2, x); }
__device__ __forceinline__ unsigned int h2u(h2 x) { return __builtin_bit_cast(unsigned int, x); }

// ---------------------------------------------------------------------------
// Fused: compact combined adjacency row (geo+sem > 0) into LDS, write CSR for
// layers 2-3, and compute GAT layer 1 attention for this row in one kernel.
// One block (256 thr) per row.
// ---------------------------------------------------------------------------
__global__ void gat_first(const float* __restrict__ geo,
                          const float* __restrict__ sem,
                          const float* __restrict__ feat,   // NN x 32
                          const float* __restrict__ W0,     // 32 x 8
                          const float* __restrict__ a0,     // 16
                          int* __restrict__ csr_idx,
                          float* __restrict__ csr_val,
                          int* __restrict__ csr_cnt,
                          float* __restrict__ enc_out) {
    const int i = blockIdx.x;
    const int t = threadIdx.x;  // 256
    __shared__ int cnt;
    __shared__ int sidx[CAP];
    __shared__ float sval[CAP];
    __shared__ float hi_s[GOUT];
    __shared__ float wsum[4][GOUT + 1];
    if (t == 0) cnt = 0;
    __syncthreads();

    const float* grow = geo + (size_t)i * NN;
    const float* srow = sem + (size_t)i * NN;
    for (int q = t; q < NN / 4; q += 256) {
        float4 g = *(const float4*)(grow + 4 * q);
        float4 s = *(const float4*)(srow + 4 * q);
        float a[4] = {g.x + s.x, g.y + s.y, g.z + s.z, g.w + s.w};
        #pragma unroll
        for (int c = 0; c < 4; ++c) {
            if (a[c] > 0.f) {
                int p = atomicAdd(&cnt, 1);
                if (p < CAP) { sidx[p] = 4 * q + c; sval[p] = a[c]; }
            }
        }
    }
    // h_i (only needed for f_src): threads 0..7
    if (t < GOUT) {
        float hv = 0.f;
        #pragma unroll 4
        for (int c = 0; c < GIN; ++c)
            hv = fmaf(feat[(size_t)i * GIN + c], W0[c * GOUT + t], hv);
        hi_s[t] = hv;
    }
    __syncthreads();

    const int c2 = cnt < CAP ? cnt : CAP;
    if (t == 0) csr_cnt[i] = c2;
    for (int p = t; p < c2; p += 256) {
        csr_idx[(size_t)i * CAP + p] = sidx[p];
        csr_val[(size_t)i * CAP + p] = sval[p];
    }
    float fsrc = 0.f;
    #pragma unroll
    for (int k = 0; k < GOUT; ++k) fsrc = fmaf(hi_s[k], a0[k], fsrc);

    // attention: one entry per thread (cnt <= 192 < 256 -> single pass)
    float den = 0.f;
    float num[GOUT] = {};
    if (t < c2) {
        int j = sidx[t];
        float a = sval[t];
        float hj[GOUT] = {};
        #pragma unroll
        for (int c4 = 0; c4 < GIN / 4; ++c4) {
            float4 e4 = *(const float4*)(feat + (size_t)j * GIN + 4 * c4);
            const float* ep = (const float*)&e4;
            #pragma unroll
            for (int c = 0; c < 4; ++c)
                #pragma unroll
                for (int k = 0; k < GOUT; ++k)
                    hj[k] = fmaf(ep[c], W0[(4 * c4 + c) * GOUT + k], hj[k]);
        }
        float fd = 0.f;
        #pragma unroll
        for (int k = 0; k < GOUT; ++k) fd = fmaf(hj[k], a0[GOUT + k], fd);
        float ev = fsrc + fd;
        ev = (ev > 0.f) ? ev : 0.2f * ev;
        ev *= a;
        float p = __expf(ev);
        den = p;
        #pragma unroll
        for (int k = 0; k < GOUT; ++k) num[k] = p * hj[k];
    }
    #pragma unroll
    for (int off = 32; off > 0; off >>= 1) {
        den += __shfl_xor(den, off, 64);
        #pragma unroll
        for (int k = 0; k < GOUT; ++k) num[k] += __shfl_xor(num[k], off, 64);
    }
    if ((t & 63) == 0) {
        wsum[t >> 6][0] = den;
        #pragma unroll
        for (int k = 0; k < GOUT; ++k) wsum[t >> 6][1 + k] = num[k];
    }
    __syncthreads();
    if (t < GOUT) {
        float L = wsum[0][0] + wsum[1][0] + wsum[2][0] + wsum[3][0];
        float v = (wsum[0][1 + t] + wsum[1][1 + t] + wsum[2][1 + t] + wsum[3][1 + t]) / L;
        enc_out[(size_t)i * GOUT + t] = (v > 0.f) ? v : (__expf(v) - 1.f);
    }
}

// ---------------------------------------------------------------------------
// GAT layers 2,3: one WAVE per row i, CSR-driven. When UV=true (layer 3),
// the wave also computes U[i,:], V[i,:] (stored as f16 for the packed-math
// MLP), A[i]=sum_k U*f2, B[i]=sum_k V*f2 (fp32 rank-1 split), and row 0's
// wave writes c = sum_k w16*f2 plus f16 copies of w16 and fc2w.
// ---------------------------------------------------------------------------
template<int IN, bool UV>
__global__ void gat_layer(const float* __restrict__ enc,
                          const float* __restrict__ W,     // IN x 8
                          const float* __restrict__ avec,  // 16
                          const int* __restrict__ csr_idx,
                          const float* __restrict__ csr_val,
                          const int* __restrict__ csr_cnt,
                          float* __restrict__ enc_out,
                          const float* __restrict__ fc1w,  // 17 x 128
                          const float* __restrict__ fc1b,  // 128
                          const float* __restrict__ fc2w,  // 128
                          _Float16* __restrict__ Uh, _Float16* __restrict__ Vh,
                          _Float16* __restrict__ wh, _Float16* __restrict__ fh,
                          float* __restrict__ Arow, float* __restrict__ Bcol,
                          float* __restrict__ cptr) {
    const int tid = threadIdx.x;            // 256 = 4 waves, 1 wave per row
    const int lane = tid & 63;
    const int i = blockIdx.x * 4 + (tid >> 6);   // 375*4 == 1500 exact

    float hv = 0.f;
    if (lane < GOUT) {
        #pragma unroll 4
        for (int c = 0; c < IN; ++c)
            hv = fmaf(enc[(size_t)i * IN + c], W[c * GOUT + lane], hv);
    }
    float hi[GOUT];
    #pragma unroll
    for (int c = 0; c < GOUT; ++c) hi[c] = __shfl(hv, c, 64);
    float fsrc = 0.f;
    #pragma unroll
    for (int c = 0; c < GOUT; ++c) fsrc = fmaf(hi[c], avec[c], fsrc);

    const int cnt = csr_cnt[i];
    float den = 0.f;
    float num[GOUT] = {};
    for (int e = lane; e < cnt; e += 64) {
        int j = csr_idx[(size_t)i * CAP + e];
        float a = csr_val[(size_t)i * CAP + e];
        float hj[GOUT] = {};
        #pragma unroll
        for (int c4 = 0; c4 < IN / 4; ++c4) {
            float4 e4 = *(const float4*)(enc + (size_t)j * IN + 4 * c4);
            const float* ep = (const float*)&e4;
            #pragma unroll
            for (int c = 0; c < 4; ++c)
                #pragma unroll
                for (int k = 0; k < GOUT; ++k)
                    hj[k] = fmaf(ep[c], W[(4 * c4 + c) * GOUT + k], hj[k]);
        }
        float fd = 0.f;
        #pragma unroll
        for (int k = 0; k < GOUT; ++k) fd = fmaf(hj[k], avec[GOUT + k], fd);
        float ev = fsrc + fd;
        ev = (ev > 0.f) ? ev : 0.2f * ev;
        ev *= a;
        float p = __expf(ev);
        den += p;
        #pragma unroll
        for (int k = 0; k < GOUT; ++k) num[k] = fmaf(p, hj[k], num[k]);
    }
    #pragma unroll
    for (int off = 32; off > 0; off >>= 1) {
        den += __shfl_xor(den, off, 64);
        #pragma unroll
        for (int k = 0; k < GOUT; ++k) num[k] += __shfl_xor(num[k], off, 64);
    }
    // elu output for this row (valid at lanes 0..7)
    float vout = 0.f;
    if (lane < GOUT) {
        float v = num[lane] / den;
        vout = (v > 0.f) ? v : (__expf(v) - 1.f);
        enc_out[(size_t)i * GOUT + lane] = vout;
    }

    if constexpr (UV) {
        float er[GOUT];
        #pragma unroll
        for (int c = 0; c < GOUT; ++c) er[c] = __shfl(vout, c, 64);
        const int kl = lane, kh = lane + 64;
        float u_lo = fc1b[kl], u_hi = fc1b[kh];
        float v_lo = 0.f, v_hi = 0.f;
        #pragma unroll
        for (int c = 0; c < GOUT; ++c) {
            u_lo = fmaf(er[c], fc1w[c * HID + kl], u_lo);
            u_hi = fmaf(er[c], fc1w[c * HID + kh], u_hi);
            v_lo = fmaf(er[c], fc1w[(GOUT + c) * HID + kl], v_lo);
            v_hi = fmaf(er[c], fc1w[(GOUT + c) * HID + kh], v_hi);
        }
        Uh[(size_t)i * HID + kl] = (_Float16)u_lo;
        Uh[(size_t)i * HID + kh] = (_Float16)u_hi;
        Vh[(size_t)i * HID + kl] = (_Float16)v_lo;
        Vh[(size_t)i * HID + kh] = (_Float16)v_hi;
        const float f_lo = fc2w[kl], f_hi = fc2w[kh];
        float ap = u_lo * f_lo + u_hi * f_hi;
        float bp = v_lo * f_lo + v_hi * f_hi;
        #pragma unroll
        for (int off = 32; off > 0; off >>= 1) {
            ap += __shfl_xor(ap, off, 64);
            bp += __shfl_xor(bp, off, 64);
        }
        if (lane == 0) { Arow[i] = ap; Bcol[i] = bp; }
        if (i == 0) {
            const float* w16g = fc1w + 2 * GOUT * HID;
            wh[kl] = (_Float16)w16g[kl];
            wh[kh] = (_Float16)w16g[kh];
            fh[kl] = (_Float16)f_lo;
            fh[kh] = (_Float16)f_hi;
            float cp = w16g[kl] * f_lo + w16g[kh] * f_hi;
            #pragma unroll
            for (int off = 32; off > 0; off >>= 1) cp += __shfl_xor(cp, off, 64);
            if (lane == 0) cptr[0] = cp;
        }
    }
}

// ---------------------------------------------------------------------------
// Pair-MLP, LDS-free lane=j, packed f16 (R10), with the scalar-load pipeline
// fixed: R10 issued one s_load_dwordx4 of U per 16 VALU (load->wait->burst
// every 32 cyc at ~100 cyc SMEM latency -> ~40% issue efficiency, the
// R8-R10 invariant). Now q-outer/r-inner: all IB row-loads batched before a
// 96-VALU burst (24 SGPRs/q; compiler can keep 2 q's in flight), one lgkm
// wait per burst instead of six.
//   per 2 k: v_pk_add_f16, v_pk_fma_f16, v_and_b32 (|.|), v_dot2_f32_f16
//   out = fc2b + 0.5*(A_i + B_j + d*c) + 0.5*sum_k |U+V+d*w16|*f2  (relu->abs)
// Grid 6 x 250 = 1500 blocks = ~5.9 waves/SIMD.
// ---------------------------------------------------------------------------
#define IB 6

__global__ __launch_bounds__(256, 6) void mlp_kernel(
        const _Float16* __restrict__ Uh, const _Float16* __restrict__ Vh,
        const _Float16* __restrict__ wh, const _Float16* __restrict__ fh,
        const float* __restrict__ Arow, const float* __restrict__ Bcol,
        const float* __restrict__ cptr,
        const float* __restrict__ dist,
        const float* __restrict__ fc2b,   // 1
        float* __restrict__ out) {
    const int tid = threadIdx.x;
    const int j = blockIdx.x * 256 + tid;        // 6*256 = 1536 covers 1500
    const int jc = j < NN ? j : NN - 1;
    const int i0 = blockIdx.y * IB;              // 250*6 = 1500 exact

    // distance strip (fp32 for epilogue + f16-pair splat for the inner fma)
    float d[IB], acc[IB];
    h2 d2[IB];
    #pragma unroll
    for (int r = 0; r < IB; ++r) {
        d[r] = dist[(size_t)(i0 + r) * NN + jc];
        acc[r] = 0.f;
        _Float16 dh = (_Float16)d[r];
        d2[r] = h2{dh, dh};
    }

    const uint4* Vrow = (const uint4*)(Vh + (size_t)jc * HID);  // 16 x uint4
    const uint4* Wt = (const uint4*)wh;
    const uint4* Ft = (const uint4*)fh;

    for (int c4 = 0; c4 < 4; ++c4) {    // 4 chunks of 32 k (8 f16 per uint4)
        uint4 vv[4], ww[4], ff[4];
        #pragma unroll
        for (int q = 0; q < 4; ++q) {
            vv[q] = Vrow[c4 * 4 + q];   // per-lane VMEM
            ww[q] = Wt[c4 * 4 + q];     // wave-uniform -> s_load
            ff[q] = Ft[c4 * 4 + q];
        }
        #pragma unroll
        for (int q = 0; q < 4; ++q) {
            // batch all IB row-loads for this q (wave-uniform -> s_load x IB)
            uint4 uu[IB];
            #pragma unroll
            for (int r = 0; r < IB; ++r)
                uu[r] = *((const uint4*)(Uh + (size_t)(i0 + r) * HID) + c4 * 4 + q);
            const unsigned int ve[4] = {vv[q].x, vv[q].y, vv[q].z, vv[q].w};
            const unsigned int we[4] = {ww[q].x, ww[q].y, ww[q].z, ww[q].w};
            const unsigned int fe[4] = {ff[q].x, ff[q].y, ff[q].z, ff[q].w};
            #pragma unroll
            for (int r = 0; r < IB; ++r) {
                const unsigned int ue[4] = {uu[r].x, uu[r].y, uu[r].z, uu[r].w};
                #pragma unroll
                for (int e = 0; e < 4; ++e) {
                    h2 t = u2h(ue[e]) + u2h(ve[e]);                       // v_pk_add_f16
                    t = __builtin_elementwise_fma(d2[r], u2h(we[e]), t);  // v_pk_fma_f16
                    t = u2h(h2u(t) & 0x7fff7fffu);                        // |.| both halves
                    acc[r] = __builtin_amdgcn_fdot2(t, u2h(fe[e]), acc[r], false);
                }
            }
        }
    }

    // epilogue: fp32 rank-1 linear half + bias, coalesced stores
    if (j < NN) {
        const float c = cptr[0];
        const float b2 = fc2b[0];
        const float Bj = Bcol[jc];
        #pragma unroll
        for (int r = 0; r < IB; ++r) {
            float lin = Arow[i0 + r] + Bj + d[r] * c;
            out[(size_t)(i0 + r) * NN + j] = fmaf(0.5f, lin + acc[r], b2);
        }
    }
}

// ---------------------------------------------------------------------------
extern "C" void kernel_launch(void* const* d_in, const int* in_sizes, int n_in,
                              void* d_out, int out_size, void* d_ws, size_t ws_size,
                              hipStream_t stream) {
    const float* geo  = (const float*)d_in[0];
    const float* sem  = (const float*)d_in[1];
    const float* feat = (const float*)d_in[2];
    // d_in[3] = region_pairs: full meshgrid -> row-major (i,j); unused
    const float* dist = (const float*)d_in[4];
    const float* W0   = (const float*)d_in[5];
    const float* W1   = (const float*)d_in[6];
    const float* W2   = (const float*)d_in[7];
    const float* a0   = (const float*)d_in[8];
    const float* a1   = (const float*)d_in[9];
    const float* a2   = (const float*)d_in[10];
    const float* fc1w = (const float*)d_in[11];
    const float* fc1b = (const float*)d_in[12];
    const float* fc2w = (const float*)d_in[13];
    const float* fc2b = (const float*)d_in[14];
    float* out = (float*)d_out;

    // workspace layout (~3.5 MB); all chunk sizes keep 16B alignment
    char* ws = (char*)d_ws;
    int*      csr_idx = (int*)ws;                     ws += sizeof(int) * NN * CAP;
    float*    csr_val = (float*)ws;                   ws += sizeof(float) * NN * CAP;
    int*      csr_cnt = (int*)ws;                     ws += sizeof(int) * NN;
    float*    encA    = (float*)ws;                   ws += sizeof(float) * NN * GOUT;
    float*    encB    = (float*)ws;                   ws += sizeof(float) * NN * GOUT;
    _Float16* Uh      = (_Float16*)ws;                ws += sizeof(_Float16) * NN * HID;
    _Float16* Vh      = (_Float16*)ws;                ws += sizeof(_Float16) * NN * HID;
    _Float16* wh      = (_Float16*)ws;                ws += sizeof(_Float16) * HID;
    _Float16* fh      = (_Float16*)ws;                ws += sizeof(_Float16) * HID;
    float*    Ar      = (float*)ws;                   ws += sizeof(float) * NN;
    float*    Bc      = (float*)ws;                   ws += sizeof(float) * NN;
    float*    cptr    = (float*)ws;

    gat_first<<<NN, 256, 0, stream>>>(geo, sem, feat, W0, a0,
                                      csr_idx, csr_val, csr_cnt, encA);
    gat_layer<GOUT, false><<<NN / 4, 256, 0, stream>>>(
        encA, W1, a1, csr_idx, csr_val, csr_cnt, encB,
        nullptr, nullptr, nullptr,
        nullptr, nullptr, nullptr, nullptr, nullptr, nullptr, nullptr);
    gat_layer<GOUT, true><<<NN / 4, 256, 0, stream>>>(
        encB, W2, a2, csr_idx, csr_val, csr_cnt, encA,
        fc1w, fc1b, fc2w, Uh, Vh, wh, fh, Ar, Bc, cptr);

    dim3 mg((NN + 255) / 256, (NN + IB - 1) / IB);   // 6 x 250
    mlp_kernel<<<mg, 256, 0, stream>>>(Uh, Vh, wh, fh, Ar, Bc, cptr,
                                       dist, fc2b, out);
}